// Round 2
// baseline (730.407 us; speedup 1.0000x reference)
//
#include <hip/hip_runtime.h>
#include <math.h>

#define V_ 50000
#define OOV_ 100
#define VX_ 50100
#define B_ 256
#define S_ 512
#define TH_ 512
#define SRC_ 512
#define KXH 1664

#define ATT_OFF ((size_t)B_ * VX_)
#define H1_OFF (ATT_OFF + (size_t)B_ * TH_)
#define C1_OFF (H1_OFF + (size_t)B_ * TH_)

typedef float f32x4 __attribute__((ext_vector_type(4)));
typedef short s16x8 __attribute__((ext_vector_type(8)));

__device__ __forceinline__ unsigned short f2bf(float f) {
    unsigned int u = __float_as_uint(f);
    u += 0x7FFFu + ((u >> 16) & 1u);
    return (unsigned short)(u >> 16);
}
__device__ __forceinline__ float fast_tanh(float x) {
    return 1.0f - 2.0f / (__expf(2.0f * x) + 1.0f);
}
__device__ __forceinline__ float sigm(float x) { return 1.0f / (1.0f + __expf(-x)); }

__device__ __forceinline__ bool get_mask(const void* m, int flag, size_t idx) {
    return flag ? (((const unsigned char*)m)[idx] != 0)
                : (((const int*)m)[idx] != 0);
}

// Builtin MFMA: compiler models MFMA->VALU hazards and inserts required
// wait-states (inline-asm MFMA did NOT get those, and the s_nop guard could
// be reordered past the epilogue reads -> corrupted accumulators).
__device__ __forceinline__ void mfma_acc(f32x4& c, s16x8 a, s16x8 b) {
    c = __builtin_amdgcn_mfma_f32_16x16x32_bf16(a, b, c, 0, 0, 0);
}

// ---- staging helpers -------------------------------------------------------
// LDS tile layout: [64 rows][128 bytes], swizzle: byte ^= ((row&7)<<4)

__device__ __forceinline__ void stage_bf16(const unsigned short* src, int ld,
                                           int row0, int k0, unsigned char* ldsbase) {
    const int tid = threadIdx.x;
    const int w = tid >> 6, lane = tid & 63;
#pragma unroll
    for (int jj = 0; jj < 2; ++jj) {
        const int qq = w * 2 + jj;               // 0..7, wave-uniform
        const int rowl = qq * 8 + (lane >> 3);
        const int su = (lane & 7) ^ (rowl & 7);  // pre-swizzled global source
        const unsigned short* g = src + (size_t)(row0 + rowl) * ld + k0 + su * 8;
        __builtin_amdgcn_global_load_lds(
            (const __attribute__((address_space(1))) void*)g,
            (__attribute__((address_space(3))) void*)(ldsbase + qq * 1024), 16, 0, 0);
    }
}

__device__ __forceinline__ void stage_f32(const float* src, int ld, int row0, int k0,
                                          int rowmax, unsigned char* ldsbase) {
    const int tid = threadIdx.x;
#pragma unroll
    for (int it = 0; it < 4; ++it) {
        const int p = it * 256 + tid;
        const int row = p >> 4;
        const int u4 = p & 15;
        int gr = row0 + row;
        gr = gr > rowmax ? rowmax : gr;
        const float4 v = *(const float4*)(src + (size_t)gr * ld + k0 + u4 * 4);
        unsigned int lo = (unsigned int)f2bf(v.x) | ((unsigned int)f2bf(v.y) << 16);
        unsigned int hi = (unsigned int)f2bf(v.z) | ((unsigned int)f2bf(v.w) << 16);
        *(uint2*)(ldsbase + row * 128 + ((u4 * 8) ^ ((row & 7) << 4))) = make_uint2(lo, hi);
    }
}

__device__ __forceinline__ void compute64(const unsigned char* Ab, const unsigned char* Bb,
                                          f32x4 acc[4]) {
    const int tid = threadIdx.x;
    const int w = tid >> 6, lane = tid & 63, lq = lane >> 4, lr = lane & 15;
#pragma unroll
    for (int ks = 0; ks < 2; ++ks) {
        const int kb = ks * 64 + lq * 16;
        const int ar = w * 16 + lr;
        s16x8 a = *(const s16x8*)(Ab + ar * 128 + (kb ^ ((ar & 7) << 4)));
#pragma unroll
        for (int ns = 0; ns < 4; ++ns) {
            const int br = ns * 16 + lr;
            s16x8 b = *(const s16x8*)(Bb + br * 128 + (kb ^ ((br & 7) << 4)));
            mfma_acc(acc[ns], a, b);
        }
    }
}

// Generic 64x64-tile GEMM core: C = A(bf16, MxK row-major) * B^T (B is NxK row-major)
template <bool BF32>
__device__ __forceinline__ void gemm_main(const unsigned short* A, int lda, const void* Bp,
                                          int ldb, int nkc, int rowmaxB, int m0, int n0,
                                          unsigned char* smem, f32x4 acc[4]) {
#pragma unroll
    for (int i = 0; i < 4; ++i) acc[i] = f32x4{0.f, 0.f, 0.f, 0.f};
    unsigned char* const A0 = smem;
    unsigned char* const A1 = smem + 8192;
    unsigned char* const B0 = smem + 16384;
    unsigned char* const B1 = smem + 24576;
    stage_bf16(A, lda, m0, 0, A0);
    if (BF32) stage_f32((const float*)Bp, ldb, n0, 0, rowmaxB, B0);
    else      stage_bf16((const unsigned short*)Bp, ldb, n0, 0, B0);
    int cur = 0;
    for (int kc = 0; kc < nkc; ++kc) {
        __syncthreads();
        if (kc + 1 < nkc) {
            stage_bf16(A, lda, m0, (kc + 1) * 64, cur ? A0 : A1);
            if (BF32) stage_f32((const float*)Bp, ldb, n0, (kc + 1) * 64, rowmaxB, cur ? B0 : B1);
            else      stage_bf16((const unsigned short*)Bp, ldb, n0, (kc + 1) * 64, cur ? B0 : B1);
        }
        compute64(cur ? A1 : A0, cur ? B1 : B0, acc);
        cur ^= 1;
    }
}

// ---- kernels ---------------------------------------------------------------

__global__ void k_init(const void* maskp, int* flag, float* rowsum) {
    __shared__ int found;
    const int tid = threadIdx.x;
    if (tid == 0) found = 0;
    __syncthreads();
    const unsigned char* mb = (const unsigned char*)maskp;
    int f = 0;
    for (int i = tid; i < B_ * S_; i += 1024)
        if ((i & 3) && mb[i]) f = 1;
    if (f) found = 1;
    __syncthreads();
    if (tid == 0) *flag = found;           // 1 => bool(1B) layout, 0 => int32 layout
    if (tid < B_) rowsum[tid] = (float)OOV_;  // OOV part of total sum
}

__global__ __launch_bounds__(256) void k_cs_part(const float* enc, const int* stok,
                                                 const int* ptok, float* cs_sum, int* cs_cnt) {
    const int b = blockIdx.x >> 2, chunk = blockIdx.x & 3;
    const int tid = threadIdx.x;
    const int prev = ptok[b];
    const float* base = enc + ((size_t)b * S_ + chunk * 128) * SRC_;
    const int* st = stok + b * S_ + chunk * 128;
    float a0 = 0.f, a1 = 0.f;
    int cnt = 0;
    for (int s = 0; s < 128; ++s) {
        if (st[s] != prev) {
            float2 v = *(const float2*)(base + (size_t)s * SRC_ + tid * 2);
            a0 += v.x; a1 += v.y; cnt++;
        }
    }
    cs_sum[(size_t)blockIdx.x * SRC_ + tid * 2] = a0;
    cs_sum[(size_t)blockIdx.x * SRC_ + tid * 2 + 1] = a1;
    if (tid == 0) cs_cnt[blockIdx.x] = cnt;
}

__global__ __launch_bounds__(256) void k_cs_final(const float* cs_sum, const int* cs_cnt,
                                                  const float* embedding, const int* ptok,
                                                  const float* pcs, const float* h0,
                                                  unsigned short* xh) {
    const int b = blockIdx.x, tid = threadIdx.x;
    const int cnt = cs_cnt[b * 4] + cs_cnt[b * 4 + 1] + cs_cnt[b * 4 + 2] + cs_cnt[b * 4 + 3];
    const float inv = 1.f / (float)cnt;
    unsigned short* row = xh + (size_t)b * KXH;
    for (int d = tid; d < 512; d += 256) {
        float s = cs_sum[(size_t)(b * 4 + 0) * SRC_ + d] + cs_sum[(size_t)(b * 4 + 1) * SRC_ + d] +
                  cs_sum[(size_t)(b * 4 + 2) * SRC_ + d] + cs_sum[(size_t)(b * 4 + 3) * SRC_ + d];
        row[640 + d] = f2bf(s * inv);              // copy_state
        row[128 + d] = f2bf(pcs[b * 512 + d]);     // prev_context_state
        row[1152 + d] = f2bf(h0[b * 512 + d]);     // h0 (for W_hh part)
    }
    if (tid < 128) {
        int tk = ptok[b];
        if (tk >= V_) tk = 1;  // UNK
        row[tid] = f2bf(embedding[(size_t)tk * 128 + tid]);
    }
}

__global__ void k_wcvt(const float* W_ih, const float* W_hh, const float* W_copy,
                       unsigned short* Wg, unsigned short* Wcb) {
    const int NWG = 2048 * KXH;
    const int NTOT = NWG + 512 * 512;
    for (int i = blockIdx.x * 256 + threadIdx.x; i < NTOT; i += gridDim.x * 256) {
        if (i < NWG) {
            int r = i / KXH, c = i - r * KXH;
            float v = (c < 1152) ? W_ih[(size_t)r * 1152 + c] : W_hh[(size_t)r * 512 + (c - 1152)];
            Wg[i] = f2bf(v);
        } else {
            int j = i - NWG;
            Wcb[j] = f2bf(W_copy[j]);
        }
    }
}

__global__ __launch_bounds__(256) void k_gates(const unsigned short* xh, const unsigned short* Wg,
                                               const float* b_ih, const float* b_hh, float* gates) {
    __shared__ __align__(16) unsigned char smem[32768];
    f32x4 acc[4];
    const int m0 = blockIdx.x * 64, n0 = blockIdx.y * 64;
    gemm_main<false>(xh, KXH, Wg, KXH, 26, 2047, m0, n0, smem, acc);
    const int tid = threadIdx.x, w = tid >> 6, lane = tid & 63, lq = lane >> 4, lr = lane & 15;
#pragma unroll
    for (int ns = 0; ns < 4; ++ns) {
        const int n = n0 + ns * 16 + lr;
        const float bb = b_ih[n] + b_hh[n];
#pragma unroll
        for (int r = 0; r < 4; ++r) {
            const int m = m0 + w * 16 + lq * 4 + r;
            gates[(size_t)m * 2048 + n] = acc[ns][r] + bb;
        }
    }
}

__global__ __launch_bounds__(256) void k_lstm(const float* gates, const float* c0, float* out,
                                              unsigned short* h1b) {
    const int idx = blockIdx.x * 256 + threadIdx.x;  // 0..131071
    const int b = idx >> 9, h = idx & 511;
    const float gi = gates[(size_t)b * 2048 + h];
    const float gf = gates[(size_t)b * 2048 + 512 + h];
    const float gg = gates[(size_t)b * 2048 + 1024 + h];
    const float go = gates[(size_t)b * 2048 + 1536 + h];
    const float c1 = sigm(gf) * c0[idx] + sigm(gi) * fast_tanh(gg);
    const float h1 = sigm(go) * fast_tanh(c1);
    out[H1_OFF + idx] = h1;
    out[C1_OFF + idx] = c1;
    h1b[idx] = f2bf(h1);
}

__global__ __launch_bounds__(256) void k_q(const unsigned short* h1b, const float* W_attn,
                                           float* qbuf) {
    __shared__ __align__(16) unsigned char smem[32768];
    f32x4 acc[4];
    const int m0 = blockIdx.x * 64, n0 = blockIdx.y * 64;
    gemm_main<true>(h1b, 512, W_attn, 512, 8, 511, m0, n0, smem, acc);
    const int tid = threadIdx.x, w = tid >> 6, lane = tid & 63, lq = lane >> 4, lr = lane & 15;
#pragma unroll
    for (int ns = 0; ns < 4; ++ns) {
        const int n = n0 + ns * 16 + lr;
#pragma unroll
        for (int r = 0; r < 4; ++r)
            qbuf[(size_t)(m0 + w * 16 + lq * 4 + r) * 512 + n] = acc[ns][r];
    }
}

__global__ __launch_bounds__(256) void k_attn(const float* enc, const float* qv,
                                              const void* maskp, const int* flagp, float* parts,
                                              float* md) {
    __shared__ __align__(16) float qs[512];
    __shared__ __align__(16) float tile[16][516];  // +4 pad: break bank conflict on dot
    __shared__ float lg[16];
    const int chunk = blockIdx.x, b = blockIdx.y;
    const int tid = threadIdx.x;
    const int flag = *flagp;
    qs[tid] = qv[b * 512 + tid];
    qs[tid + 256] = qv[b * 512 + tid + 256];
    float M = -INFINITY, den = 0.f, cA = 0.f, cB = 0.f;
    const int g = tid >> 4, j = tid & 15;
    for (int t = 0; t < 8; ++t) {
        const int sbase = chunk * 128 + t * 16;
        __syncthreads();
#pragma unroll
        for (int i = 0; i < 8; ++i) {
            int p = i * 256 + tid;
            int row = p >> 7, u = p & 127;
            *(float4*)&tile[row][u * 4] =
                *(const float4*)(enc + ((size_t)b * S_ + sbase + row) * SRC_ + u * 4);
        }
        __syncthreads();
        float a = 0.f;
#pragma unroll
        for (int k = 0; k < 32; ++k) a += qs[j + k * 16] * tile[g][j + k * 16];
        a += __shfl_xor(a, 1, 16);
        a += __shfl_xor(a, 2, 16);
        a += __shfl_xor(a, 4, 16);
        a += __shfl_xor(a, 8, 16);
        if (j == 0)
            lg[g] = get_mask(maskp, flag, (size_t)b * S_ + sbase + g) ? -INFINITY : a;
        __syncthreads();
        float tmax = lg[0];
#pragma unroll
        for (int s = 1; s < 16; ++s) tmax = fmaxf(tmax, lg[s]);
        if (tmax != -INFINITY) {
            const float newM = fmaxf(M, tmax);
            const float scale = __expf(M - newM);  // M==-inf -> 0
            cA *= scale; cB *= scale; den *= scale; M = newM;
#pragma unroll
            for (int s = 0; s < 16; ++s) {
                const float lv = lg[s];
                const float p = (lv == -INFINITY) ? 0.f : __expf(lv - M);
                den += p;
                cA += p * tile[s][tid];
                cB += p * tile[s][tid + 256];
            }
        }
    }
    parts[((size_t)chunk * B_ + b) * 512 + tid] = cA;
    parts[((size_t)chunk * B_ + b) * 512 + tid + 256] = cB;
    if (tid == 0) {
        md[(chunk * B_ + b) * 2] = M;
        md[(chunk * B_ + b) * 2 + 1] = den;
    }
}

__global__ __launch_bounds__(256) void k_attn_merge(const float* parts, const float* md,
                                                    const unsigned short* h1b, unsigned short* ch) {
    const int b = blockIdx.x, tid = threadIdx.x;
    float Ms[4], Ds[4], M = -INFINITY;
#pragma unroll
    for (int jj = 0; jj < 4; ++jj) {
        Ms[jj] = md[(jj * B_ + b) * 2];
        Ds[jj] = md[(jj * B_ + b) * 2 + 1];
        M = fmaxf(M, Ms[jj]);
    }
    float den = 0.f, sc[4];
#pragma unroll
    for (int jj = 0; jj < 4; ++jj) {
        sc[jj] = __expf(Ms[jj] - M);  // -inf -> 0
        den += Ds[jj] * sc[jj];
    }
    const float inv = 1.f / den;
    for (int d = tid; d < 512; d += 256) {
        float c = 0.f;
#pragma unroll
        for (int jj = 0; jj < 4; ++jj) c += parts[((size_t)jj * B_ + b) * 512 + d] * sc[jj];
        ch[(size_t)b * 1024 + d] = f2bf(c * inv);
    }
    ch[(size_t)b * 1024 + 512 + tid] = h1b[b * 512 + tid];
    ch[(size_t)b * 1024 + 512 + 256 + tid] = h1b[b * 512 + 256 + tid];
}

__global__ __launch_bounds__(256) void k_attnout(const unsigned short* ch, const float* W_out,
                                                 const float* b_out, float* out,
                                                 unsigned short* aob) {
    __shared__ __align__(16) unsigned char smem[32768];
    f32x4 acc[4];
    const int m0 = blockIdx.x * 64, n0 = blockIdx.y * 64;
    gemm_main<true>(ch, 1024, W_out, 1024, 16, 511, m0, n0, smem, acc);
    const int tid = threadIdx.x, w = tid >> 6, lane = tid & 63, lq = lane >> 4, lr = lane & 15;
#pragma unroll
    for (int ns = 0; ns < 4; ++ns) {
        const int n = n0 + ns * 16 + lr;
        const float bb = b_out[n];
#pragma unroll
        for (int r = 0; r < 4; ++r) {
            const int m = m0 + w * 16 + lq * 4 + r;
            const float t = fast_tanh(acc[ns][r] + bb);
            out[ATT_OFF + (size_t)m * 512 + n] = t;
            aob[(size_t)m * 512 + n] = f2bf(t);
        }
    }
}

__global__ __launch_bounds__(256) void k_gen(const unsigned short* aob, const float* W_gen,
                                             float* out, float* rowsum) {
    __shared__ __align__(16) unsigned char smem[32768];
    f32x4 acc[4];
    const int m0 = blockIdx.x * 64, n0 = blockIdx.y * 64;
    gemm_main<true>(aob, 512, W_gen, 512, 8, V_ - 1, m0, n0, smem, acc);
    const int tid = threadIdx.x, w = tid >> 6, lane = tid & 63, lq = lane >> 4, lr = lane & 15;
    float rp[4] = {0.f, 0.f, 0.f, 0.f};
#pragma unroll
    for (int ns = 0; ns < 4; ++ns) {
        const int n = n0 + ns * 16 + lr;
        if (n < V_) {
#pragma unroll
            for (int r = 0; r < 4; ++r) {
                const float v = __expf(acc[ns][r]);
                out[(size_t)(m0 + w * 16 + lq * 4 + r) * VX_ + n] = v;
                rp[r] += v;
            }
        }
    }
#pragma unroll
    for (int r = 0; r < 4; ++r) {
        rp[r] += __shfl_xor(rp[r], 1, 16);
        rp[r] += __shfl_xor(rp[r], 2, 16);
        rp[r] += __shfl_xor(rp[r], 4, 16);
        rp[r] += __shfl_xor(rp[r], 8, 16);
    }
    if (lr == 0) {
#pragma unroll
        for (int r = 0; r < 4; ++r) atomicAdd(&rowsum[m0 + w * 16 + lq * 4 + r], rp[r]);
    }
}

__global__ void k_oov(float* out) {
    const int p = blockIdx.x * 256 + threadIdx.x;
    if (p < B_ * OOV_) {
        const int b = p / OOV_, j = p - b * OOV_;
        out[(size_t)b * VX_ + V_ + j] = 1.0f;
    }
}

__global__ __launch_bounds__(256) void k_copyseq(const float* enc, const unsigned short* Wcb,
                                                 const float* ao, const int* stok,
                                                 const void* maskp, const int* flagp, float* out,
                                                 float* rowsum) {
    __shared__ __align__(16) unsigned char smem[65536 + 16384 + 2048];
    unsigned char* const Alds = smem;              // [64][1024B] enc tile (bf16, swizzled)
    unsigned char* const Bb0 = smem + 65536;
    unsigned char* const Bb1 = smem + 65536 + 8192;
    float* const attn_s = (float*)(smem + 65536 + 16384);
    const int sblk = blockIdx.x, b = blockIdx.y;
    const int tid = threadIdx.x;
    const int flag = *flagp;
    attn_s[tid] = ao[b * 512 + tid];
    attn_s[tid + 256] = ao[b * 512 + tid + 256];
    {   // stage A: 64 s-rows x 512 k, f32 -> bf16, swizzled
        const float* src = enc + ((size_t)b * S_ + sblk * 64) * SRC_;
        for (int it = 0; it < 32; ++it) {
            const int p = it * 256 + tid;
            const int row = p >> 7, u4 = p & 127;
            const float4 v = *(const float4*)(src + (size_t)row * SRC_ + u4 * 4);
            unsigned int lo = (unsigned int)f2bf(v.x) | ((unsigned int)f2bf(v.y) << 16);
            unsigned int hi = (unsigned int)f2bf(v.z) | ((unsigned int)f2bf(v.w) << 16);
            *(uint2*)(Alds + row * 1024 + ((u4 * 8) ^ ((row & 7) << 4))) = make_uint2(lo, hi);
        }
    }
    stage_bf16(Wcb, 512, 0, 0, Bb0);
    const int w = tid >> 6, lane = tid & 63, lq = lane >> 4, lr = lane & 15;
    float part[4] = {0.f, 0.f, 0.f, 0.f};
    int cur = 0;
    for (int ht = 0; ht < 8; ++ht) {
        f32x4 acc[4];
#pragma unroll
        for (int i = 0; i < 4; ++i) acc[i] = f32x4{0.f, 0.f, 0.f, 0.f};
        for (int kc = 0; kc < 8; ++kc) {
            __syncthreads();
            int nh = ht, nk = kc + 1;
            if (nk == 8) { nh = ht + 1; nk = 0; }
            if (nh < 8) stage_bf16(Wcb, 512, nh * 64, nk * 64, cur ? Bb0 : Bb1);
            const unsigned char* Bc = cur ? Bb1 : Bb0;
#pragma unroll
            for (int ks = 0; ks < 2; ++ks) {
                const int kbA = (kc * 2 + ks) * 64 + lq * 16;
                const int ar = w * 16 + lr;
                s16x8 a = *(const s16x8*)(Alds + ar * 1024 + (kbA ^ ((ar & 7) << 4)));
                const int kbB = ks * 64 + lq * 16;
#pragma unroll
                for (int ns = 0; ns < 4; ++ns) {
                    const int br = ns * 16 + lr;
                    s16x8 bfr = *(const s16x8*)(Bc + br * 128 + (kbB ^ ((br & 7) << 4)));
                    mfma_acc(acc[ns], a, bfr);
                }
            }
            cur ^= 1;
        }
#pragma unroll
        for (int ns = 0; ns < 4; ++ns) {
            const float aw = attn_s[ht * 64 + ns * 16 + lr];
#pragma unroll
            for (int r = 0; r < 4; ++r) part[r] += fast_tanh(acc[ns][r]) * aw;
        }
    }
#pragma unroll
    for (int r = 0; r < 4; ++r) {
        part[r] += __shfl_xor(part[r], 1, 16);
        part[r] += __shfl_xor(part[r], 2, 16);
        part[r] += __shfl_xor(part[r], 4, 16);
        part[r] += __shfl_xor(part[r], 8, 16);
    }
    if (lr == 0) {
        float lsum = 0.f;
#pragma unroll
        for (int r = 0; r < 4; ++r) {
            const int s = sblk * 64 + w * 16 + lq * 4 + r;
            if (!get_mask(maskp, flag, (size_t)b * S_ + s)) {
                const float v = __expf(part[r]);
                const int tk = stok[b * S_ + s];
                atomicAdd(&out[(size_t)b * VX_ + tk], v);
                lsum += v;
            }
        }
        atomicAdd(&rowsum[b], lsum);
    }
}

__global__ __launch_bounds__(256) void k_final(float* out, const float* rowsum) {
    const int b = blockIdx.y;
    const float ls = logf(rowsum[b]);
    int v = blockIdx.x * 1024 + threadIdx.x;
#pragma unroll
    for (int i = 0; i < 4; ++i, v += 256) {
        if (v < VX_) {
            const size_t o = (size_t)b * VX_ + v;
            out[o] = logf(out[o]) - ls;
        }
    }
}

// ---- host ------------------------------------------------------------------

extern "C" void kernel_launch(void* const* d_in, const int* in_sizes, int n_in, void* d_out,
                              int out_size, void* d_ws, size_t ws_size, hipStream_t stream) {
    const float* embedding = (const float*)d_in[0];
    const float* W_ih = (const float*)d_in[1];
    const float* W_hh = (const float*)d_in[2];
    const float* b_ih = (const float*)d_in[3];
    const float* b_hh = (const float*)d_in[4];
    const float* W_attn = (const float*)d_in[5];
    const float* W_out = (const float*)d_in[6];
    const float* b_out = (const float*)d_in[7];
    const float* W_copy = (const float*)d_in[8];
    // d_in[9] = W_incopy: provably dead in the reference (tanh(0)=0 on unmatched,
    // matched positions masked to -inf => softmax is uniform over unmatched).
    const float* W_gen = (const float*)d_in[10];
    const float* enc = (const float*)d_in[11];
    const float* pcs = (const float*)d_in[12];
    const float* h0 = (const float*)d_in[13];
    const float* c0 = (const float*)d_in[14];
    const int* ptok = (const int*)d_in[15];
    const int* stok = (const int*)d_in[16];
    const void* maskp = d_in[17];
    float* out = (float*)d_out;

    char* ws = (char*)d_ws;
    size_t off = 0;
    auto alloc = [&](size_t bytes) {
        size_t o = off;
        off += (bytes + 255) & ~(size_t)255;
        return o;
    };
    int* flag = (int*)(ws + alloc(4));
    float* rowsum = (float*)(ws + alloc(B_ * 4));
    float* cs_sum = (float*)(ws + alloc((size_t)1024 * SRC_ * 4));
    int* cs_cnt = (int*)(ws + alloc(1024 * 4));
    unsigned short* xh = (unsigned short*)(ws + alloc((size_t)B_ * KXH * 2));
    unsigned short* Wg = (unsigned short*)(ws + alloc((size_t)2048 * KXH * 2));
    unsigned short* Wcb = (unsigned short*)(ws + alloc((size_t)512 * 512 * 2));
    float* gates = (float*)(ws + alloc((size_t)B_ * 2048 * 4));
    unsigned short* h1b = (unsigned short*)(ws + alloc((size_t)B_ * 512 * 2));
    float* qbuf = (float*)(ws + alloc((size_t)B_ * 512 * 4));
    float* parts = (float*)(ws + alloc((size_t)4 * B_ * 512 * 4));
    float* md = (float*)(ws + alloc((size_t)4 * B_ * 2 * 4));
    unsigned short* ch = (unsigned short*)(ws + alloc((size_t)B_ * 1024 * 2));
    unsigned short* aob = (unsigned short*)(ws + alloc((size_t)B_ * 512 * 2));
    (void)ws_size; (void)n_in; (void)in_sizes; (void)out_size;

    hipLaunchKernelGGL(k_init, dim3(1), dim3(1024), 0, stream, maskp, flag, rowsum);
    hipLaunchKernelGGL(k_cs_part, dim3(1024), dim3(256), 0, stream, enc, stok, ptok, cs_sum, cs_cnt);
    hipLaunchKernelGGL(k_wcvt, dim3(4096), dim3(256), 0, stream, W_ih, W_hh, W_copy, Wg, Wcb);
    hipLaunchKernelGGL(k_cs_final, dim3(256), dim3(256), 0, stream, cs_sum, cs_cnt, embedding,
                       ptok, pcs, h0, xh);
    hipLaunchKernelGGL(k_gates, dim3(4, 32), dim3(256), 0, stream, xh, Wg, b_ih, b_hh, gates);
    hipLaunchKernelGGL(k_lstm, dim3(512), dim3(256), 0, stream, gates, c0, out, h1b);
    hipLaunchKernelGGL(k_q, dim3(4, 8), dim3(256), 0, stream, h1b, W_attn, qbuf);
    hipLaunchKernelGGL(k_attn, dim3(4, 256), dim3(256), 0, stream, enc, qbuf, maskp, flag, parts, md);
    hipLaunchKernelGGL(k_attn_merge, dim3(256), dim3(256), 0, stream, parts, md, h1b, ch);
    hipLaunchKernelGGL(k_attnout, dim3(4, 8), dim3(256), 0, stream, ch, W_out, b_out, out, aob);
    hipLaunchKernelGGL(k_gen, dim3(4, 782), dim3(256), 0, stream, aob, W_gen, out, rowsum);
    hipLaunchKernelGGL(k_oov, dim3(100), dim3(256), 0, stream, out);
    hipLaunchKernelGGL(k_copyseq, dim3(8, 256), dim3(256), 0, stream, enc, Wcb, out + ATT_OFF,
                       stok, maskp, flag, out, rowsum);
    hipLaunchKernelGGL(k_final, dim3(49, 256), dim3(256), 0, stream, out, rowsum);
}

// Round 3
// 625.350 us; speedup vs baseline: 1.1680x; 1.1680x over previous
//
#include <hip/hip_runtime.h>
#include <math.h>

#define V_ 50000
#define OOV_ 100
#define VX_ 50100
#define B_ 256
#define S_ 512
#define TH_ 512
#define SRC_ 512
#define KXH 1664

#define ATT_OFF ((size_t)B_ * VX_)
#define H1_OFF (ATT_OFF + (size_t)B_ * TH_)
#define C1_OFF (H1_OFF + (size_t)B_ * TH_)

typedef float f32x4 __attribute__((ext_vector_type(4)));
typedef short s16x8 __attribute__((ext_vector_type(8)));

__device__ __forceinline__ unsigned short f2bf(float f) {
    unsigned int u = __float_as_uint(f);
    u += 0x7FFFu + ((u >> 16) & 1u);
    return (unsigned short)(u >> 16);
}
__device__ __forceinline__ float fast_tanh(float x) {
    return 1.0f - 2.0f / (__expf(2.0f * x) + 1.0f);
}
__device__ __forceinline__ float sigm(float x) { return 1.0f / (1.0f + __expf(-x)); }

__device__ __forceinline__ bool get_mask(const void* m, int flag, size_t idx) {
    return flag ? (((const unsigned char*)m)[idx] != 0)
                : (((const int*)m)[idx] != 0);
}

// Builtin MFMA: compiler models MFMA->VALU hazards (inline-asm version corrupted
// accumulators -- round 1->2 lesson).
__device__ __forceinline__ void mfma_acc(f32x4& c, s16x8 a, s16x8 b) {
    c = __builtin_amdgcn_mfma_f32_16x16x32_bf16(a, b, c, 0, 0, 0);
}

// ---- staging helpers -------------------------------------------------------
// LDS tile layout: [rows][128 bytes], swizzle: byte ^= ((row&7)<<4)

__device__ __forceinline__ void stage_bf16(const unsigned short* src, int ld,
                                           int row0, int k0, unsigned char* ldsbase) {
    const int tid = threadIdx.x;
    const int w = tid >> 6, lane = tid & 63;
#pragma unroll
    for (int jj = 0; jj < 2; ++jj) {
        const int qq = w * 2 + jj;               // 0..7, wave-uniform
        const int rowl = qq * 8 + (lane >> 3);
        const int su = (lane & 7) ^ (rowl & 7);  // pre-swizzled global source
        const unsigned short* g = src + (size_t)(row0 + rowl) * ld + k0 + su * 8;
        __builtin_amdgcn_global_load_lds(
            (const __attribute__((address_space(1))) void*)g,
            (__attribute__((address_space(3))) void*)(ldsbase + qq * 1024), 16, 0, 0);
    }
}

// 128-row variant (16 KB tile), same layout/swizzle
__device__ __forceinline__ void stage_bf16_128(const unsigned short* src, int ld,
                                               int k0, unsigned char* ldsbase) {
    const int tid = threadIdx.x;
    const int w = tid >> 6, lane = tid & 63;
#pragma unroll
    for (int jj = 0; jj < 4; ++jj) {
        const int qq = w * 4 + jj;               // 0..15, wave-uniform
        const int rowl = qq * 8 + (lane >> 3);   // 0..127
        const int su = (lane & 7) ^ (rowl & 7);
        const unsigned short* g = src + (size_t)rowl * ld + k0 + su * 8;
        __builtin_amdgcn_global_load_lds(
            (const __attribute__((address_space(1))) void*)g,
            (__attribute__((address_space(3))) void*)(ldsbase + qq * 1024), 16, 0, 0);
    }
}

__device__ __forceinline__ void stage_f32(const float* src, int ld, int row0, int k0,
                                          int rowmax, unsigned char* ldsbase) {
    const int tid = threadIdx.x;
#pragma unroll
    for (int it = 0; it < 4; ++it) {
        const int p = it * 256 + tid;
        const int row = p >> 4;
        const int u4 = p & 15;
        int gr = row0 + row;
        gr = gr > rowmax ? rowmax : gr;
        const float4 v = *(const float4*)(src + (size_t)gr * ld + k0 + u4 * 4);
        unsigned int lo = (unsigned int)f2bf(v.x) | ((unsigned int)f2bf(v.y) << 16);
        unsigned int hi = (unsigned int)f2bf(v.z) | ((unsigned int)f2bf(v.w) << 16);
        *(uint2*)(ldsbase + row * 128 + ((u4 * 8) ^ ((row & 7) << 4))) = make_uint2(lo, hi);
    }
}

__device__ __forceinline__ void compute64(const unsigned char* Ab, const unsigned char* Bb,
                                          f32x4 acc[4]) {
    const int tid = threadIdx.x;
    const int w = tid >> 6, lane = tid & 63, lq = lane >> 4, lr = lane & 15;
#pragma unroll
    for (int ks = 0; ks < 2; ++ks) {
        const int kb = ks * 64 + lq * 16;
        const int ar = w * 16 + lr;
        s16x8 a = *(const s16x8*)(Ab + ar * 128 + (kb ^ ((ar & 7) << 4)));
#pragma unroll
        for (int ns = 0; ns < 4; ++ns) {
            const int br = ns * 16 + lr;
            s16x8 b = *(const s16x8*)(Bb + br * 128 + (kb ^ ((br & 7) << 4)));
            mfma_acc(acc[ns], a, b);
        }
    }
}

// Generic 64x64-tile GEMM core: C = A(bf16, MxK row-major) * B^T (B is NxK row-major)
template <bool BF32>
__device__ __forceinline__ void gemm_main(const unsigned short* A, int lda, const void* Bp,
                                          int ldb, int nkc, int rowmaxB, int m0, int n0,
                                          unsigned char* smem, f32x4 acc[4]) {
#pragma unroll
    for (int i = 0; i < 4; ++i) acc[i] = f32x4{0.f, 0.f, 0.f, 0.f};
    unsigned char* const A0 = smem;
    unsigned char* const A1 = smem + 8192;
    unsigned char* const B0 = smem + 16384;
    unsigned char* const B1 = smem + 24576;
    stage_bf16(A, lda, m0, 0, A0);
    if (BF32) stage_f32((const float*)Bp, ldb, n0, 0, rowmaxB, B0);
    else      stage_bf16((const unsigned short*)Bp, ldb, n0, 0, B0);
    int cur = 0;
    for (int kc = 0; kc < nkc; ++kc) {
        __syncthreads();
        if (kc + 1 < nkc) {
            stage_bf16(A, lda, m0, (kc + 1) * 64, cur ? A0 : A1);
            if (BF32) stage_f32((const float*)Bp, ldb, n0, (kc + 1) * 64, rowmaxB, cur ? B0 : B1);
            else      stage_bf16((const unsigned short*)Bp, ldb, n0, (kc + 1) * 64, cur ? B0 : B1);
        }
        compute64(cur ? A1 : A0, cur ? B1 : B0, acc);
        cur ^= 1;
    }
}

// ---- kernels ---------------------------------------------------------------

__global__ void k_init(const void* maskp, int* flag, float* rowsum) {
    __shared__ int found;
    const int tid = threadIdx.x;
    if (tid == 0) found = 0;
    __syncthreads();
    const unsigned char* mb = (const unsigned char*)maskp;
    int f = 0;
    for (int i = tid; i < B_ * S_; i += 1024)
        if ((i & 3) && mb[i]) f = 1;
    if (f) found = 1;
    __syncthreads();
    if (tid == 0) *flag = found;           // 1 => bool(1B) layout, 0 => int32 layout
    if (tid < B_) rowsum[tid] = (float)OOV_;  // OOV part of total sum
}

__global__ void k_zero(float* p) {
    p[blockIdx.x * 256 + threadIdx.x] = 0.f;
}

__global__ __launch_bounds__(256) void k_cs_part(const float* enc, const int* stok,
                                                 const int* ptok, float* cs_sum, int* cs_cnt) {
    const int b = blockIdx.x >> 2, chunk = blockIdx.x & 3;
    const int tid = threadIdx.x;
    const int prev = ptok[b];
    const float* base = enc + ((size_t)b * S_ + chunk * 128) * SRC_;
    const int* st = stok + b * S_ + chunk * 128;
    float a0 = 0.f, a1 = 0.f;
    int cnt = 0;
    for (int s = 0; s < 128; ++s) {
        if (st[s] != prev) {
            float2 v = *(const float2*)(base + (size_t)s * SRC_ + tid * 2);
            a0 += v.x; a1 += v.y; cnt++;
        }
    }
    cs_sum[(size_t)blockIdx.x * SRC_ + tid * 2] = a0;
    cs_sum[(size_t)blockIdx.x * SRC_ + tid * 2 + 1] = a1;
    if (tid == 0) cs_cnt[blockIdx.x] = cnt;
}

__global__ __launch_bounds__(256) void k_cs_final(const float* cs_sum, const int* cs_cnt,
                                                  const float* embedding, const int* ptok,
                                                  const float* pcs, const float* h0,
                                                  unsigned short* xh) {
    const int b = blockIdx.x, tid = threadIdx.x;
    const int cnt = cs_cnt[b * 4] + cs_cnt[b * 4 + 1] + cs_cnt[b * 4 + 2] + cs_cnt[b * 4 + 3];
    const float inv = 1.f / (float)cnt;
    unsigned short* row = xh + (size_t)b * KXH;
    for (int d = tid; d < 512; d += 256) {
        float s = cs_sum[(size_t)(b * 4 + 0) * SRC_ + d] + cs_sum[(size_t)(b * 4 + 1) * SRC_ + d] +
                  cs_sum[(size_t)(b * 4 + 2) * SRC_ + d] + cs_sum[(size_t)(b * 4 + 3) * SRC_ + d];
        row[640 + d] = f2bf(s * inv);              // copy_state
        row[128 + d] = f2bf(pcs[b * 512 + d]);     // prev_context_state
        row[1152 + d] = f2bf(h0[b * 512 + d]);     // h0 (for W_hh part)
    }
    if (tid < 128) {
        int tk = ptok[b];
        if (tk >= V_) tk = 1;  // UNK
        row[tid] = f2bf(embedding[(size_t)tk * 128 + tid]);
    }
}

__global__ void k_wcvt(const float* W_ih, const float* W_hh, const float* W_copy,
                       unsigned short* Wg, unsigned short* Wcb) {
    const int NWG = 2048 * KXH;
    const int NTOT = NWG + 512 * 512;
    for (int i = blockIdx.x * 256 + threadIdx.x; i < NTOT; i += gridDim.x * 256) {
        if (i < NWG) {
            int r = i / KXH, c = i - r * KXH;
            float v = (c < 1152) ? W_ih[(size_t)r * 1152 + c] : W_hh[(size_t)r * 512 + (c - 1152)];
            Wg[i] = f2bf(v);
        } else {
            int j = i - NWG;
            Wcb[j] = f2bf(W_copy[j]);
        }
    }
}

__global__ __launch_bounds__(256) void k_gates(const unsigned short* xh, const unsigned short* Wg,
                                               const float* b_ih, const float* b_hh, float* gates) {
    __shared__ __align__(16) unsigned char smem[32768];
    f32x4 acc[4];
    const int m0 = blockIdx.x * 64, n0 = blockIdx.y * 64;
    gemm_main<false>(xh, KXH, Wg, KXH, 26, 2047, m0, n0, smem, acc);
    const int tid = threadIdx.x, w = tid >> 6, lane = tid & 63, lq = lane >> 4, lr = lane & 15;
#pragma unroll
    for (int ns = 0; ns < 4; ++ns) {
        const int n = n0 + ns * 16 + lr;
        const float bb = b_ih[n] + b_hh[n];
#pragma unroll
        for (int r = 0; r < 4; ++r) {
            const int m = m0 + w * 16 + lq * 4 + r;
            gates[(size_t)m * 2048 + n] = acc[ns][r] + bb;
        }
    }
}

__global__ __launch_bounds__(256) void k_lstm(const float* gates, const float* c0, float* out,
                                              unsigned short* h1b) {
    const int idx = blockIdx.x * 256 + threadIdx.x;  // 0..131071
    const int b = idx >> 9, h = idx & 511;
    const float gi = gates[(size_t)b * 2048 + h];
    const float gf = gates[(size_t)b * 2048 + 512 + h];
    const float gg = gates[(size_t)b * 2048 + 1024 + h];
    const float go = gates[(size_t)b * 2048 + 1536 + h];
    const float c1 = sigm(gf) * c0[idx] + sigm(gi) * fast_tanh(gg);
    const float h1 = sigm(go) * fast_tanh(c1);
    out[H1_OFF + idx] = h1;
    out[C1_OFF + idx] = c1;
    h1b[idx] = f2bf(h1);
}

__global__ __launch_bounds__(256) void k_q(const unsigned short* h1b, const float* W_attn,
                                           float* qbuf) {
    __shared__ __align__(16) unsigned char smem[32768];
    f32x4 acc[4];
    const int m0 = blockIdx.x * 64, n0 = blockIdx.y * 64;
    gemm_main<true>(h1b, 512, W_attn, 512, 8, 511, m0, n0, smem, acc);
    const int tid = threadIdx.x, w = tid >> 6, lane = tid & 63, lq = lane >> 4, lr = lane & 15;
#pragma unroll
    for (int ns = 0; ns < 4; ++ns) {
        const int n = n0 + ns * 16 + lr;
#pragma unroll
        for (int r = 0; r < 4; ++r)
            qbuf[(size_t)(m0 + w * 16 + lq * 4 + r) * 512 + n] = acc[ns][r];
    }
}

__global__ __launch_bounds__(256) void k_attn(const float* enc, const float* qv,
                                              const void* maskp, const int* flagp, float* parts,
                                              float* md) {
    __shared__ __align__(16) float qs[512];
    __shared__ __align__(16) float tile[16][516];  // +4 pad: break bank conflict on dot
    __shared__ float lg[16];
    const int chunk = blockIdx.x, b = blockIdx.y;
    const int tid = threadIdx.x;
    const int flag = *flagp;
    qs[tid] = qv[b * 512 + tid];
    qs[tid + 256] = qv[b * 512 + tid + 256];
    float M = -INFINITY, den = 0.f, cA = 0.f, cB = 0.f;
    const int g = tid >> 4, j = tid & 15;
    for (int t = 0; t < 8; ++t) {
        const int sbase = chunk * 128 + t * 16;
        __syncthreads();
#pragma unroll
        for (int i = 0; i < 8; ++i) {
            int p = i * 256 + tid;
            int row = p >> 7, u = p & 127;
            *(float4*)&tile[row][u * 4] =
                *(const float4*)(enc + ((size_t)b * S_ + sbase + row) * SRC_ + u * 4);
        }
        __syncthreads();
        float a = 0.f;
#pragma unroll
        for (int k = 0; k < 32; ++k) a += qs[j + k * 16] * tile[g][j + k * 16];
        a += __shfl_xor(a, 1, 16);
        a += __shfl_xor(a, 2, 16);
        a += __shfl_xor(a, 4, 16);
        a += __shfl_xor(a, 8, 16);
        if (j == 0)
            lg[g] = get_mask(maskp, flag, (size_t)b * S_ + sbase + g) ? -INFINITY : a;
        __syncthreads();
        float tmax = lg[0];
#pragma unroll
        for (int s = 1; s < 16; ++s) tmax = fmaxf(tmax, lg[s]);
        if (tmax != -INFINITY) {
            const float newM = fmaxf(M, tmax);
            const float scale = __expf(M - newM);  // M==-inf -> 0
            cA *= scale; cB *= scale; den *= scale; M = newM;
#pragma unroll
            for (int s = 0; s < 16; ++s) {
                const float lv = lg[s];
                const float p = (lv == -INFINITY) ? 0.f : __expf(lv - M);
                den += p;
                cA += p * tile[s][tid];
                cB += p * tile[s][tid + 256];
            }
        }
    }
    parts[((size_t)chunk * B_ + b) * 512 + tid] = cA;
    parts[((size_t)chunk * B_ + b) * 512 + tid + 256] = cB;
    if (tid == 0) {
        md[(chunk * B_ + b) * 2] = M;
        md[(chunk * B_ + b) * 2 + 1] = den;
    }
}

__global__ __launch_bounds__(256) void k_attn_merge(const float* parts, const float* md,
                                                    const unsigned short* h1b, unsigned short* ch) {
    const int b = blockIdx.x, tid = threadIdx.x;
    float Ms[4], Ds[4], M = -INFINITY;
#pragma unroll
    for (int jj = 0; jj < 4; ++jj) {
        Ms[jj] = md[(jj * B_ + b) * 2];
        Ds[jj] = md[(jj * B_ + b) * 2 + 1];
        M = fmaxf(M, Ms[jj]);
    }
    float den = 0.f, sc[4];
#pragma unroll
    for (int jj = 0; jj < 4; ++jj) {
        sc[jj] = __expf(Ms[jj] - M);  // -inf -> 0
        den += Ds[jj] * sc[jj];
    }
    const float inv = 1.f / den;
    for (int d = tid; d < 512; d += 256) {
        float c = 0.f;
#pragma unroll
        for (int jj = 0; jj < 4; ++jj) c += parts[((size_t)jj * B_ + b) * 512 + d] * sc[jj];
        ch[(size_t)b * 1024 + d] = f2bf(c * inv);
    }
    ch[(size_t)b * 1024 + 512 + tid] = h1b[b * 512 + tid];
    ch[(size_t)b * 1024 + 512 + 256 + tid] = h1b[b * 512 + 256 + tid];
}

__global__ __launch_bounds__(256) void k_attnout(const unsigned short* ch, const float* W_out,
                                                 const float* b_out, float* out,
                                                 unsigned short* aob) {
    __shared__ __align__(16) unsigned char smem[32768];
    f32x4 acc[4];
    const int m0 = blockIdx.x * 64, n0 = blockIdx.y * 64;
    gemm_main<true>(ch, 1024, W_out, 1024, 16, 511, m0, n0, smem, acc);
    const int tid = threadIdx.x, w = tid >> 6, lane = tid & 63, lq = lane >> 4, lr = lane & 15;
#pragma unroll
    for (int ns = 0; ns < 4; ++ns) {
        const int n = n0 + ns * 16 + lr;
        const float bb = b_out[n];
#pragma unroll
        for (int r = 0; r < 4; ++r) {
            const int m = m0 + w * 16 + lq * 4 + r;
            const float t = fast_tanh(acc[ns][r] + bb);
            out[ATT_OFF + (size_t)m * 512 + n] = t;
            aob[(size_t)m * 512 + n] = f2bf(t);
        }
    }
}

__global__ __launch_bounds__(256) void k_gen(const unsigned short* aob, const float* W_gen,
                                             float* out, float* rowsum) {
    __shared__ __align__(16) unsigned char smem[32768];
    f32x4 acc[4];
    const int m0 = blockIdx.x * 64, n0 = blockIdx.y * 64;
    gemm_main<true>(aob, 512, W_gen, 512, 8, V_ - 1, m0, n0, smem, acc);
    const int tid = threadIdx.x, w = tid >> 6, lane = tid & 63, lq = lane >> 4, lr = lane & 15;
    float rp[4] = {0.f, 0.f, 0.f, 0.f};
#pragma unroll
    for (int ns = 0; ns < 4; ++ns) {
        const int n = n0 + ns * 16 + lr;
        if (n < V_) {
#pragma unroll
            for (int r = 0; r < 4; ++r) {
                const float v = __expf(acc[ns][r]);
                out[(size_t)(m0 + w * 16 + lq * 4 + r) * VX_ + n] = v;
                rp[r] += v;
            }
        }
    }
#pragma unroll
    for (int r = 0; r < 4; ++r) {
        rp[r] += __shfl_xor(rp[r], 1, 16);
        rp[r] += __shfl_xor(rp[r], 2, 16);
        rp[r] += __shfl_xor(rp[r], 4, 16);
        rp[r] += __shfl_xor(rp[r], 8, 16);
    }
    if (lr == 0) {
#pragma unroll
        for (int r = 0; r < 4; ++r) atomicAdd(&rowsum[m0 + w * 16 + lq * 4 + r], rp[r]);
    }
}

__global__ void k_oov(float* out) {
    const int p = blockIdx.x * 256 + threadIdx.x;
    if (p < B_ * OOV_) {
        const int b = p / OOV_, j = p - b * OOV_;
        out[(size_t)b * VX_ + V_ + j] = 1.0f;
    }
}

// copy_seq GEMM: logit[m, :] partial = sum_n tanh( enc[m,:] @ Wcb[n,:]^T ) * ao[b,n]
// M = B*S = 131072, N = 512 (grid.y covers 128-col slices), K = 512.
// m97-style 128x128x64 tile, 4 waves in 2x2, acc 4x4 frags of 16x16x32.
// A (enc, f32) is reg-staged with fused f32->bf16 convert (T14 issue-early/
// write-late); B (Wcb, bf16) staged via global_load_lds. Both XOR-swizzled.
__global__ __launch_bounds__(256) void k_copyseq(const float* enc, const unsigned short* Wcb,
                                                 const float* ao, float* logit) {
    __shared__ __align__(16) unsigned char smem[65536];
    unsigned char* const A0 = smem;
    unsigned char* const A1 = smem + 16384;
    unsigned char* const B0 = smem + 32768;
    unsigned char* const B1 = smem + 49152;
    const int m0 = blockIdx.x * 128;
    const int n0 = blockIdx.y * 128;
    const int b = blockIdx.x >> 2;  // 4 M-tiles per batch row (512/128)
    const int tid = threadIdx.x;
    const int w = tid >> 6, lane = tid & 63;
    const int wm = w >> 1, wn = w & 1, lq = lane >> 4, lr = lane & 15;
    const float* Asrc = enc + (size_t)m0 * 512;

    f32x4 acc[4][4];
#pragma unroll
    for (int mi = 0; mi < 4; ++mi)
#pragma unroll
        for (int ni = 0; ni < 4; ++ni) acc[mi][ni] = f32x4{0.f, 0.f, 0.f, 0.f};

    // A reg-stage: thread p handles row=p>>3 (0..127), 8-elem chunk u=p&7
    const int arow_t = tid >> 3, au_t = tid & 7;

    // prologue: stage k-chunk 0 of A (load+cvt+write) and B
    {
#pragma unroll
        for (int it = 0; it < 4; ++it) {
            const int row = arow_t + it * 32;
            const float* g = Asrc + (size_t)row * 512 + au_t * 8;
            const float4 v0 = *(const float4*)g;
            const float4 v1 = *(const float4*)(g + 4);
            uint4 pk;
            pk.x = (unsigned int)f2bf(v0.x) | ((unsigned int)f2bf(v0.y) << 16);
            pk.y = (unsigned int)f2bf(v0.z) | ((unsigned int)f2bf(v0.w) << 16);
            pk.z = (unsigned int)f2bf(v1.x) | ((unsigned int)f2bf(v1.y) << 16);
            pk.w = (unsigned int)f2bf(v1.z) | ((unsigned int)f2bf(v1.w) << 16);
            *(uint4*)(A0 + row * 128 + ((au_t * 16) ^ ((row & 7) << 4))) = pk;
        }
        stage_bf16_128(Wcb + (size_t)n0 * 512, 512, 0, B0);
    }

    for (int kc = 0; kc < 8; ++kc) {
        __syncthreads();
        const unsigned char* Ac = (kc & 1) ? A1 : A0;
        const unsigned char* Bc = (kc & 1) ? B1 : B0;
        unsigned char* An = (kc & 1) ? A0 : A1;
        unsigned char* Bn = (kc & 1) ? B0 : B1;
        float4 va[4], vb[4];
        if (kc < 7) {  // issue next-tile global loads early (latency hides under MFMA)
            const int k0 = (kc + 1) * 64;
#pragma unroll
            for (int it = 0; it < 4; ++it) {
                const int row = arow_t + it * 32;
                const float* g = Asrc + (size_t)row * 512 + k0 + au_t * 8;
                va[it] = *(const float4*)g;
                vb[it] = *(const float4*)(g + 4);
            }
            stage_bf16_128(Wcb + (size_t)n0 * 512, 512, k0, Bn);
        }
        // compute current tile
#pragma unroll
        for (int ks = 0; ks < 2; ++ks) {
            const int kb = ks * 64 + lq * 16;
            s16x8 afr[4], bfr[4];
#pragma unroll
            for (int mi = 0; mi < 4; ++mi) {
                const int ar = wm * 64 + mi * 16 + lr;
                afr[mi] = *(const s16x8*)(Ac + ar * 128 + (kb ^ ((ar & 7) << 4)));
            }
#pragma unroll
            for (int ni = 0; ni < 4; ++ni) {
                const int br = wn * 64 + ni * 16 + lr;
                bfr[ni] = *(const s16x8*)(Bc + br * 128 + (kb ^ ((br & 7) << 4)));
            }
#pragma unroll
            for (int mi = 0; mi < 4; ++mi)
#pragma unroll
                for (int ni = 0; ni < 4; ++ni) mfma_acc(acc[mi][ni], afr[mi], bfr[ni]);
        }
        if (kc < 7) {  // write-late: convert + ds_write after compute, before barrier
#pragma unroll
            for (int it = 0; it < 4; ++it) {
                const int row = arow_t + it * 32;
                uint4 pk;
                pk.x = (unsigned int)f2bf(va[it].x) | ((unsigned int)f2bf(va[it].y) << 16);
                pk.y = (unsigned int)f2bf(va[it].z) | ((unsigned int)f2bf(va[it].w) << 16);
                pk.z = (unsigned int)f2bf(vb[it].x) | ((unsigned int)f2bf(vb[it].y) << 16);
                pk.w = (unsigned int)f2bf(vb[it].z) | ((unsigned int)f2bf(vb[it].w) << 16);
                *(uint4*)(An + row * 128 + ((au_t * 16) ^ ((row & 7) << 4))) = pk;
            }
        }
    }

    // epilogue: p[s] += sum over this wave's 64 n-cols of tanh(P)*ao
    float aow[4];
#pragma unroll
    for (int ni = 0; ni < 4; ++ni) aow[ni] = ao[b * 512 + n0 + wn * 64 + ni * 16 + lr];
#pragma unroll
    for (int mi = 0; mi < 4; ++mi) {
#pragma unroll
        for (int r = 0; r < 4; ++r) {
            float p = 0.f;
#pragma unroll
            for (int ni = 0; ni < 4; ++ni) p += fast_tanh(acc[mi][ni][r]) * aow[ni];
            p += __shfl_xor(p, 1, 16);
            p += __shfl_xor(p, 2, 16);
            p += __shfl_xor(p, 4, 16);
            p += __shfl_xor(p, 8, 16);
            if (lr == 0)
                atomicAdd(&logit[(size_t)m0 + wm * 64 + mi * 16 + lq * 4 + r], p);
        }
    }
}

__global__ __launch_bounds__(256) void k_scatter(const float* logit, const int* stok,
                                                 const void* maskp, const int* flagp,
                                                 float* out, float* rowsum) {
    const int idx = blockIdx.x * 256 + threadIdx.x;  // block spans 256 idx within one b
    const int b = idx >> 9;
    const int flag = *flagp;
    float v = 0.f;
    if (!get_mask(maskp, flag, idx)) {
        v = __expf(logit[idx]);
        atomicAdd(&out[(size_t)b * VX_ + stok[idx]], v);
    }
    float s = v;
#pragma unroll
    for (int o = 1; o < 64; o <<= 1) s += __shfl_xor(s, o, 64);
    if ((threadIdx.x & 63) == 0) atomicAdd(&rowsum[b], s);
}

__global__ __launch_bounds__(256) void k_final(float* out, const float* rowsum) {
    const int b = blockIdx.y;
    const float ls = logf(rowsum[b]);
    int v = blockIdx.x * 1024 + threadIdx.x;
#pragma unroll
    for (int i = 0; i < 4; ++i, v += 256) {
        if (v < VX_) {
            const size_t o = (size_t)b * VX_ + v;
            out[o] = logf(out[o]) - ls;
        }
    }
}

// ---- host ------------------------------------------------------------------

extern "C" void kernel_launch(void* const* d_in, const int* in_sizes, int n_in, void* d_out,
                              int out_size, void* d_ws, size_t ws_size, hipStream_t stream) {
    const float* embedding = (const float*)d_in[0];
    const float* W_ih = (const float*)d_in[1];
    const float* W_hh = (const float*)d_in[2];
    const float* b_ih = (const float*)d_in[3];
    const float* b_hh = (const float*)d_in[4];
    const float* W_attn = (const float*)d_in[5];
    const float* W_out = (const float*)d_in[6];
    const float* b_out = (const float*)d_in[7];
    const float* W_copy = (const float*)d_in[8];
    // d_in[9] = W_incopy: provably dead in the reference (tanh(0)=0 on unmatched,
    // matched positions masked to -inf => softmax is uniform over unmatched).
    const float* W_gen = (const float*)d_in[10];
    const float* enc = (const float*)d_in[11];
    const float* pcs = (const float*)d_in[12];
    const float* h0 = (const float*)d_in[13];
    const float* c0 = (const float*)d_in[14];
    const int* ptok = (const int*)d_in[15];
    const int* stok = (const int*)d_in[16];
    const void* maskp = d_in[17];
    float* out = (float*)d_out;

    char* ws = (char*)d_ws;
    size_t off = 0;
    auto alloc = [&](size_t bytes) {
        size_t o = off;
        off += (bytes + 255) & ~(size_t)255;
        return o;
    };
    int* flag = (int*)(ws + alloc(4));
    float* rowsum = (float*)(ws + alloc(B_ * 4));
    float* cs_sum = (float*)(ws + alloc((size_t)1024 * SRC_ * 4));
    int* cs_cnt = (int*)(ws + alloc(1024 * 4));
    unsigned short* xh = (unsigned short*)(ws + alloc((size_t)B_ * KXH * 2));
    unsigned short* Wg = (unsigned short*)(ws + alloc((size_t)2048 * KXH * 2));
    unsigned short* Wcb = (unsigned short*)(ws + alloc((size_t)512 * 512 * 2));
    float* gates = (float*)(ws + alloc((size_t)B_ * 2048 * 4));
    unsigned short* h1b = (unsigned short*)(ws + alloc((size_t)B_ * 512 * 2));
    float* qbuf = (float*)(ws + alloc((size_t)B_ * 512 * 4));
    float* parts = (float*)(ws + alloc((size_t)4 * B_ * 512 * 4));
    float* md = (float*)(ws + alloc((size_t)4 * B_ * 2 * 4));
    unsigned short* ch = (unsigned short*)(ws + alloc((size_t)B_ * 1024 * 2));
    unsigned short* aob = (unsigned short*)(ws + alloc((size_t)B_ * 512 * 2));
    float* logit = (float*)(ws + alloc((size_t)B_ * S_ * 4));
    (void)ws_size; (void)n_in; (void)in_sizes; (void)out_size;

    hipLaunchKernelGGL(k_init, dim3(1), dim3(1024), 0, stream, maskp, flag, rowsum);
    hipLaunchKernelGGL(k_zero, dim3(512), dim3(256), 0, stream, logit);
    hipLaunchKernelGGL(k_cs_part, dim3(1024), dim3(256), 0, stream, enc, stok, ptok, cs_sum, cs_cnt);
    hipLaunchKernelGGL(k_wcvt, dim3(4096), dim3(256), 0, stream, W_ih, W_hh, W_copy, Wg, Wcb);
    hipLaunchKernelGGL(k_cs_final, dim3(256), dim3(256), 0, stream, cs_sum, cs_cnt, embedding,
                       ptok, pcs, h0, xh);
    hipLaunchKernelGGL(k_gates, dim3(4, 32), dim3(256), 0, stream, xh, Wg, b_ih, b_hh, gates);
    hipLaunchKernelGGL(k_lstm, dim3(512), dim3(256), 0, stream, gates, c0, out, h1b);
    hipLaunchKernelGGL(k_q, dim3(4, 8), dim3(256), 0, stream, h1b, W_attn, qbuf);
    hipLaunchKernelGGL(k_attn, dim3(4, 256), dim3(256), 0, stream, enc, qbuf, maskp, flag, parts, md);
    hipLaunchKernelGGL(k_attn_merge, dim3(256), dim3(256), 0, stream, parts, md, h1b, ch);
    hipLaunchKernelGGL(k_attnout, dim3(4, 8), dim3(256), 0, stream, ch, W_out, b_out, out, aob);
    hipLaunchKernelGGL(k_gen, dim3(4, 782), dim3(256), 0, stream, aob, W_gen, out, rowsum);
    hipLaunchKernelGGL(k_oov, dim3(100), dim3(256), 0, stream, out);
    hipLaunchKernelGGL(k_copyseq, dim3(1024, 4), dim3(256), 0, stream, enc, Wcb,
                       out + ATT_OFF, logit);
    hipLaunchKernelGGL(k_scatter, dim3(512), dim3(256), 0, stream, logit, stok, maskp, flag,
                       out, rowsum);
    hipLaunchKernelGGL(k_final, dim3(49, 256), dim3(256), 0, stream, out, rowsum);
}

// Round 4
// 517.470 us; speedup vs baseline: 1.4115x; 1.2085x over previous
//
#include <hip/hip_runtime.h>
#include <math.h>

#define V_ 50000
#define OOV_ 100
#define VX_ 50100
#define B_ 256
#define S_ 512
#define TH_ 512
#define SRC_ 512
#define KXH 1664

#define ATT_OFF ((size_t)B_ * VX_)
#define H1_OFF (ATT_OFF + (size_t)B_ * TH_)
#define C1_OFF (H1_OFF + (size_t)B_ * TH_)

typedef float f32x4 __attribute__((ext_vector_type(4)));
typedef short s16x8 __attribute__((ext_vector_type(8)));

__device__ __forceinline__ unsigned short f2bf(float f) {
    unsigned int u = __float_as_uint(f);
    u += 0x7FFFu + ((u >> 16) & 1u);
    return (unsigned short)(u >> 16);
}
__device__ __forceinline__ float fast_tanh(float x) {
    return 1.0f - 2.0f / (__expf(2.0f * x) + 1.0f);
}
__device__ __forceinline__ float sigm(float x) { return 1.0f / (1.0f + __expf(-x)); }

__device__ __forceinline__ bool get_mask(const void* m, int flag, size_t idx) {
    return flag ? (((const unsigned char*)m)[idx] != 0)
                : (((const int*)m)[idx] != 0);
}

// Builtin MFMA: compiler models MFMA->VALU hazards (inline-asm version corrupted
// accumulators -- round 1->2 lesson).
__device__ __forceinline__ void mfma_acc(f32x4& c, s16x8 a, s16x8 b) {
    c = __builtin_amdgcn_mfma_f32_16x16x32_bf16(a, b, c, 0, 0, 0);
}

// ---- staging helpers -------------------------------------------------------
// LDS tile layout: [rows][128 bytes], swizzle: byte ^= ((row&7)<<4)

__device__ __forceinline__ void stage_bf16(const unsigned short* src, int ld,
                                           int row0, int k0, unsigned char* ldsbase) {
    const int tid = threadIdx.x;
    const int w = tid >> 6, lane = tid & 63;
#pragma unroll
    for (int jj = 0; jj < 2; ++jj) {
        const int qq = w * 2 + jj;               // 0..7, wave-uniform
        const int rowl = qq * 8 + (lane >> 3);
        const int su = (lane & 7) ^ (rowl & 7);  // pre-swizzled global source
        const unsigned short* g = src + (size_t)(row0 + rowl) * ld + k0 + su * 8;
        __builtin_amdgcn_global_load_lds(
            (const __attribute__((address_space(1))) void*)g,
            (__attribute__((address_space(3))) void*)(ldsbase + qq * 1024), 16, 0, 0);
    }
}

// 128-row variant (16 KB tile), same layout/swizzle
__device__ __forceinline__ void stage_bf16_128(const unsigned short* src, int ld,
                                               int k0, unsigned char* ldsbase) {
    const int tid = threadIdx.x;
    const int w = tid >> 6, lane = tid & 63;
#pragma unroll
    for (int jj = 0; jj < 4; ++jj) {
        const int qq = w * 4 + jj;               // 0..15, wave-uniform
        const int rowl = qq * 8 + (lane >> 3);   // 0..127
        const int su = (lane & 7) ^ (rowl & 7);
        const unsigned short* g = src + (size_t)rowl * ld + k0 + su * 8;
        __builtin_amdgcn_global_load_lds(
            (const __attribute__((address_space(1))) void*)g,
            (__attribute__((address_space(3))) void*)(ldsbase + qq * 1024), 16, 0, 0);
    }
}

__device__ __forceinline__ void stage_f32(const float* src, int ld, int row0, int k0,
                                          int rowmax, unsigned char* ldsbase) {
    const int tid = threadIdx.x;
#pragma unroll
    for (int it = 0; it < 4; ++it) {
        const int p = it * 256 + tid;
        const int row = p >> 4;
        const int u4 = p & 15;
        int gr = row0 + row;
        gr = gr > rowmax ? rowmax : gr;
        const float4 v = *(const float4*)(src + (size_t)gr * ld + k0 + u4 * 4);
        unsigned int lo = (unsigned int)f2bf(v.x) | ((unsigned int)f2bf(v.y) << 16);
        unsigned int hi = (unsigned int)f2bf(v.z) | ((unsigned int)f2bf(v.w) << 16);
        *(uint2*)(ldsbase + row * 128 + ((u4 * 8) ^ ((row & 7) << 4))) = make_uint2(lo, hi);
    }
}

__device__ __forceinline__ void compute64(const unsigned char* Ab, const unsigned char* Bb,
                                          f32x4 acc[4]) {
    const int tid = threadIdx.x;
    const int w = tid >> 6, lane = tid & 63, lq = lane >> 4, lr = lane & 15;
#pragma unroll
    for (int ks = 0; ks < 2; ++ks) {
        const int kb = ks * 64 + lq * 16;
        const int ar = w * 16 + lr;
        s16x8 a = *(const s16x8*)(Ab + ar * 128 + (kb ^ ((ar & 7) << 4)));
#pragma unroll
        for (int ns = 0; ns < 4; ++ns) {
            const int br = ns * 16 + lr;
            s16x8 b = *(const s16x8*)(Bb + br * 128 + (kb ^ ((br & 7) << 4)));
            mfma_acc(acc[ns], a, b);
        }
    }
}

// Generic 64x64-tile GEMM core: C = A(bf16, MxK row-major) * B^T (B is NxK row-major)
template <bool BF32>
__device__ __forceinline__ void gemm_main(const unsigned short* A, int lda, const void* Bp,
                                          int ldb, int nkc, int rowmaxB, int m0, int n0,
                                          unsigned char* smem, f32x4 acc[4]) {
#pragma unroll
    for (int i = 0; i < 4; ++i) acc[i] = f32x4{0.f, 0.f, 0.f, 0.f};
    unsigned char* const A0 = smem;
    unsigned char* const A1 = smem + 8192;
    unsigned char* const B0 = smem + 16384;
    unsigned char* const B1 = smem + 24576;
    stage_bf16(A, lda, m0, 0, A0);
    if (BF32) stage_f32((const float*)Bp, ldb, n0, 0, rowmaxB, B0);
    else      stage_bf16((const unsigned short*)Bp, ldb, n0, 0, B0);
    int cur = 0;
    for (int kc = 0; kc < nkc; ++kc) {
        __syncthreads();
        if (kc + 1 < nkc) {
            stage_bf16(A, lda, m0, (kc + 1) * 64, cur ? A0 : A1);
            if (BF32) stage_f32((const float*)Bp, ldb, n0, (kc + 1) * 64, rowmaxB, cur ? B0 : B1);
            else      stage_bf16((const unsigned short*)Bp, ldb, n0, (kc + 1) * 64, cur ? B0 : B1);
        }
        compute64(cur ? A1 : A0, cur ? B1 : B0, acc);
        cur ^= 1;
    }
}

// ---- kernels ---------------------------------------------------------------

__global__ void k_zero(float* logit, int* flag, float* rowsum) {
    const int bid = blockIdx.x, tid = threadIdx.x;
    if (bid < 512) logit[bid * 256 + tid] = 0.f;
    else if (bid == 512) {
        if (tid < B_) rowsum[tid] = (float)OOV_;  // OOV part of total sum
        if (tid == 0) *flag = 0;
    }
}

__global__ void k_scan(const void* maskp, int* flag) {
    const unsigned char* mb = (const unsigned char*)maskp;
    int f = 0;
    for (int i = blockIdx.x * 256 + threadIdx.x; i < B_ * S_; i += 64 * 256)
        if ((i & 3) && mb[i]) f = 1;
    if (f) atomicOr(flag, 1);  // 1 => bool(1B) layout, 0 => int32 layout
}

// Streams all of enc: computes copy_state partial means AND (optionally) the
// one-time f32->bf16 materialization of enc (ebf) for attn + copyseq.
__global__ __launch_bounds__(256) void k_cs_part(const float* enc, const int* stok,
                                                 const int* ptok, float* cs_sum, int* cs_cnt,
                                                 unsigned short* ebf, int do_cvt) {
    __shared__ float comb[512];
    __shared__ int cc[2];
    const int bid = blockIdx.x;
    const int b = bid >> 2, chunk = bid & 3;
    const int tid = threadIdx.x;
    const int h = tid >> 7, d0 = (tid & 127) * 4;
    const int prev = ptok[b];
    const float* base = enc + ((size_t)b * S_ + chunk * 128) * SRC_;
    const int* st = stok + b * S_ + chunk * 128;
    unsigned short* eb = ebf + ((size_t)b * S_ + chunk * 128) * SRC_;
    float a0 = 0.f, a1 = 0.f, a2 = 0.f, a3 = 0.f;
    int cnt = 0;
    for (int s2 = 0; s2 < 64; ++s2) {
        const int s = s2 * 2 + h;                 // wave-uniform branch below
        const float4 v = *(const float4*)(base + (size_t)s * SRC_ + d0);
        if (st[s] != prev) { a0 += v.x; a1 += v.y; a2 += v.z; a3 += v.w; ++cnt; }
        if (do_cvt) {
            uint2 pk;
            pk.x = (unsigned int)f2bf(v.x) | ((unsigned int)f2bf(v.y) << 16);
            pk.y = (unsigned int)f2bf(v.z) | ((unsigned int)f2bf(v.w) << 16);
            *(uint2*)(eb + (size_t)s * SRC_ + d0) = pk;
        }
    }
    if (h == 0) {
        comb[d0] = a0; comb[d0 + 1] = a1; comb[d0 + 2] = a2; comb[d0 + 3] = a3;
        if (tid == 0) cc[0] = cnt;
    }
    __syncthreads();
    if (h == 1) {
        comb[d0] += a0; comb[d0 + 1] += a1; comb[d0 + 2] += a2; comb[d0 + 3] += a3;
        if (tid == 128) cc[1] = cnt;
    }
    __syncthreads();
    cs_sum[(size_t)bid * SRC_ + tid] = comb[tid];
    cs_sum[(size_t)bid * SRC_ + 256 + tid] = comb[256 + tid];
    if (tid == 0) cs_cnt[bid] = cc[0] + cc[1];
}

__global__ __launch_bounds__(256) void k_cs_final(const float* cs_sum, const int* cs_cnt,
                                                  const float* embedding, const int* ptok,
                                                  const float* pcs, const float* h0,
                                                  unsigned short* xh) {
    const int b = blockIdx.x, tid = threadIdx.x;
    const int cnt = cs_cnt[b * 4] + cs_cnt[b * 4 + 1] + cs_cnt[b * 4 + 2] + cs_cnt[b * 4 + 3];
    const float inv = 1.f / (float)cnt;
    unsigned short* row = xh + (size_t)b * KXH;
    for (int d = tid; d < 512; d += 256) {
        float s = cs_sum[(size_t)(b * 4 + 0) * SRC_ + d] + cs_sum[(size_t)(b * 4 + 1) * SRC_ + d] +
                  cs_sum[(size_t)(b * 4 + 2) * SRC_ + d] + cs_sum[(size_t)(b * 4 + 3) * SRC_ + d];
        row[640 + d] = f2bf(s * inv);              // copy_state
        row[128 + d] = f2bf(pcs[b * 512 + d]);     // prev_context_state
        row[1152 + d] = f2bf(h0[b * 512 + d]);     // h0 (for W_hh part)
    }
    if (tid < 128) {
        int tk = ptok[b];
        if (tk >= V_) tk = 1;  // UNK
        row[tid] = f2bf(embedding[(size_t)tk * 128 + tid]);
    }
}

__global__ void k_wcvt(const float* W_ih, const float* W_hh, const float* W_copy,
                       unsigned short* Wg, unsigned short* Wcb) {
    const int NWG = 2048 * KXH;
    const int NTOT = NWG + 512 * 512;
    for (int i = blockIdx.x * 256 + threadIdx.x; i < NTOT; i += gridDim.x * 256) {
        if (i < NWG) {
            int r = i / KXH, c = i - r * KXH;
            float v = (c < 1152) ? W_ih[(size_t)r * 1152 + c] : W_hh[(size_t)r * 512 + (c - 1152)];
            Wg[i] = f2bf(v);
        } else {
            int j = i - NWG;
            Wcb[j] = f2bf(W_copy[j]);
        }
    }
}

__global__ __launch_bounds__(256) void k_gates(const unsigned short* xh, const unsigned short* Wg,
                                               const float* b_ih, const float* b_hh, float* gates) {
    __shared__ __align__(16) unsigned char smem[32768];
    f32x4 acc[4];
    const int m0 = blockIdx.x * 64, n0 = blockIdx.y * 64;
    gemm_main<false>(xh, KXH, Wg, KXH, 26, 2047, m0, n0, smem, acc);
    const int tid = threadIdx.x, w = tid >> 6, lane = tid & 63, lq = lane >> 4, lr = lane & 15;
#pragma unroll
    for (int ns = 0; ns < 4; ++ns) {
        const int n = n0 + ns * 16 + lr;
        const float bb = b_ih[n] + b_hh[n];
#pragma unroll
        for (int r = 0; r < 4; ++r) {
            const int m = m0 + w * 16 + lq * 4 + r;
            gates[(size_t)m * 2048 + n] = acc[ns][r] + bb;
        }
    }
}

__global__ __launch_bounds__(256) void k_lstm(const float* gates, const float* c0, float* out,
                                              unsigned short* h1b) {
    const int idx = blockIdx.x * 256 + threadIdx.x;  // 0..131071
    const int b = idx >> 9, h = idx & 511;
    const float gi = gates[(size_t)b * 2048 + h];
    const float gf = gates[(size_t)b * 2048 + 512 + h];
    const float gg = gates[(size_t)b * 2048 + 1024 + h];
    const float go = gates[(size_t)b * 2048 + 1536 + h];
    const float c1 = sigm(gf) * c0[idx] + sigm(gi) * fast_tanh(gg);
    const float h1 = sigm(go) * fast_tanh(c1);
    out[H1_OFF + idx] = h1;
    out[C1_OFF + idx] = c1;
    h1b[idx] = f2bf(h1);
}

__global__ __launch_bounds__(256) void k_q(const unsigned short* h1b, const float* W_attn,
                                           float* qbuf) {
    __shared__ __align__(16) unsigned char smem[32768];
    f32x4 acc[4];
    const int m0 = blockIdx.x * 64, n0 = blockIdx.y * 64;
    gemm_main<true>(h1b, 512, W_attn, 512, 8, 511, m0, n0, smem, acc);
    const int tid = threadIdx.x, w = tid >> 6, lane = tid & 63, lq = lane >> 4, lr = lane & 15;
#pragma unroll
    for (int ns = 0; ns < 4; ++ns) {
        const int n = n0 + ns * 16 + lr;
#pragma unroll
        for (int r = 0; r < 4; ++r)
            qbuf[(size_t)(m0 + w * 16 + lq * 4 + r) * 512 + n] = acc[ns][r];
    }
}

__global__ __launch_bounds__(256) void k_attn(const float* enc, const unsigned short* ebf,
                                              const int use_ebf, const float* qv,
                                              const void* maskp, const int* flagp, float* parts,
                                              float* md) {
    __shared__ __align__(16) float qs[512];
    __shared__ __align__(16) float tile[16][516];  // +4 pad: break bank conflict on dot
    __shared__ float lg[16];
    const int chunk = blockIdx.x, b = blockIdx.y;
    const int tid = threadIdx.x;
    const int flag = *flagp;
    qs[tid] = qv[b * 512 + tid];
    qs[tid + 256] = qv[b * 512 + tid + 256];
    float M = -INFINITY, den = 0.f, cA = 0.f, cB = 0.f;
    const int g = tid >> 4, j = tid & 15;
    for (int t = 0; t < 8; ++t) {
        const int sbase = chunk * 128 + t * 16;
        __syncthreads();
        if (use_ebf) {
#pragma unroll
            for (int i = 0; i < 4; ++i) {
                const int p = i * 256 + tid;
                const int row = p >> 6, u = p & 63;
                const uint4 q = *(const uint4*)(ebf + ((size_t)b * S_ + sbase + row) * 512 + u * 8);
                float* tp = &tile[row][u * 8];
                tp[0] = __uint_as_float(q.x << 16);
                tp[1] = __uint_as_float(q.x & 0xffff0000u);
                tp[2] = __uint_as_float(q.y << 16);
                tp[3] = __uint_as_float(q.y & 0xffff0000u);
                tp[4] = __uint_as_float(q.z << 16);
                tp[5] = __uint_as_float(q.z & 0xffff0000u);
                tp[6] = __uint_as_float(q.w << 16);
                tp[7] = __uint_as_float(q.w & 0xffff0000u);
            }
        } else {
#pragma unroll
            for (int i = 0; i < 8; ++i) {
                int p = i * 256 + tid;
                int row = p >> 7, u = p & 127;
                *(float4*)&tile[row][u * 4] =
                    *(const float4*)(enc + ((size_t)b * S_ + sbase + row) * SRC_ + u * 4);
            }
        }
        __syncthreads();
        float a = 0.f;
#pragma unroll
        for (int k = 0; k < 32; ++k) a += qs[j + k * 16] * tile[g][j + k * 16];
        a += __shfl_xor(a, 1, 16);
        a += __shfl_xor(a, 2, 16);
        a += __shfl_xor(a, 4, 16);
        a += __shfl_xor(a, 8, 16);
        if (j == 0)
            lg[g] = get_mask(maskp, flag, (size_t)b * S_ + sbase + g) ? -INFINITY : a;
        __syncthreads();
        float tmax = lg[0];
#pragma unroll
        for (int s = 1; s < 16; ++s) tmax = fmaxf(tmax, lg[s]);
        if (tmax != -INFINITY) {
            const float newM = fmaxf(M, tmax);
            const float scale = __expf(M - newM);  // M==-inf -> 0
            cA *= scale; cB *= scale; den *= scale; M = newM;
#pragma unroll
            for (int s = 0; s < 16; ++s) {
                const float lv = lg[s];
                const float p = (lv == -INFINITY) ? 0.f : __expf(lv - M);
                den += p;
                cA += p * tile[s][tid];
                cB += p * tile[s][tid + 256];
            }
        }
    }
    parts[((size_t)chunk * B_ + b) * 512 + tid] = cA;
    parts[((size_t)chunk * B_ + b) * 512 + tid + 256] = cB;
    if (tid == 0) {
        md[(chunk * B_ + b) * 2] = M;
        md[(chunk * B_ + b) * 2 + 1] = den;
    }
}

__global__ __launch_bounds__(256) void k_attn_merge(const float* parts, const float* md,
                                                    const unsigned short* h1b, unsigned short* ch) {
    const int b = blockIdx.x, tid = threadIdx.x;
    float Ms[4], Ds[4], M = -INFINITY;
#pragma unroll
    for (int jj = 0; jj < 4; ++jj) {
        Ms[jj] = md[(jj * B_ + b) * 2];
        Ds[jj] = md[(jj * B_ + b) * 2 + 1];
        M = fmaxf(M, Ms[jj]);
    }
    float den = 0.f, sc[4];
#pragma unroll
    for (int jj = 0; jj < 4; ++jj) {
        sc[jj] = __expf(Ms[jj] - M);  // -inf -> 0
        den += Ds[jj] * sc[jj];
    }
    const float inv = 1.f / den;
    for (int d = tid; d < 512; d += 256) {
        float c = 0.f;
#pragma unroll
        for (int jj = 0; jj < 4; ++jj) c += parts[((size_t)jj * B_ + b) * 512 + d] * sc[jj];
        ch[(size_t)b * 1024 + d] = f2bf(c * inv);
    }
    ch[(size_t)b * 1024 + 512 + tid] = h1b[b * 512 + tid];
    ch[(size_t)b * 1024 + 512 + 256 + tid] = h1b[b * 512 + 256 + tid];
}

__global__ __launch_bounds__(256) void k_attnout(const unsigned short* ch, const float* W_out,
                                                 const float* b_out, float* out,
                                                 unsigned short* aob) {
    __shared__ __align__(16) unsigned char smem[32768];
    f32x4 acc[4];
    const int m0 = blockIdx.x * 64, n0 = blockIdx.y * 64;
    gemm_main<true>(ch, 1024, W_out, 1024, 16, 511, m0, n0, smem, acc);
    const int tid = threadIdx.x, w = tid >> 6, lane = tid & 63, lq = lane >> 4, lr = lane & 15;
#pragma unroll
    for (int ns = 0; ns < 4; ++ns) {
        const int n = n0 + ns * 16 + lr;
        const float bb = b_out[n];
#pragma unroll
        for (int r = 0; r < 4; ++r) {
            const int m = m0 + w * 16 + lq * 4 + r;
            const float t = fast_tanh(acc[ns][r] + bb);
            out[ATT_OFF + (size_t)m * 512 + n] = t;
            aob[(size_t)m * 512 + n] = f2bf(t);
        }
    }
}

__global__ __launch_bounds__(256) void k_gen(const unsigned short* aob, const float* W_gen,
                                             float* out, float* rowsum) {
    __shared__ __align__(16) unsigned char smem[32768];
    f32x4 acc[4];
    const int m0 = blockIdx.x * 64, n0 = blockIdx.y * 64;
    gemm_main<true>(aob, 512, W_gen, 512, 8, V_ - 1, m0, n0, smem, acc);
    const int tid = threadIdx.x, w = tid >> 6, lane = tid & 63, lq = lane >> 4, lr = lane & 15;
    float rp[4] = {0.f, 0.f, 0.f, 0.f};
#pragma unroll
    for (int ns = 0; ns < 4; ++ns) {
        const int n = n0 + ns * 16 + lr;
        if (n < V_) {
#pragma unroll
            for (int r = 0; r < 4; ++r) {
                const float v = __expf(acc[ns][r]);
                out[(size_t)(m0 + w * 16 + lq * 4 + r) * VX_ + n] = v;
                rp[r] += v;
            }
        }
    }
#pragma unroll
    for (int r = 0; r < 4; ++r) {
        rp[r] += __shfl_xor(rp[r], 1, 16);
        rp[r] += __shfl_xor(rp[r], 2, 16);
        rp[r] += __shfl_xor(rp[r], 4, 16);
        rp[r] += __shfl_xor(rp[r], 8, 16);
    }
    if (lr == 0) {
#pragma unroll
        for (int r = 0; r < 4; ++r) atomicAdd(&rowsum[m0 + w * 16 + lq * 4 + r], rp[r]);
    }
}

__global__ void k_oov(float* out) {
    const int p = blockIdx.x * 256 + threadIdx.x;
    if (p < B_ * OOV_) {
        const int b = p / OOV_, j = p - b * OOV_;
        out[(size_t)b * VX_ + V_ + j] = 1.0f;
    }
}

// copy_seq GEMM v3: A from pre-converted bf16 enc (ebf) via global_load_lds
// (no VALU convert in the hot loop). Grid (n=4, m=1024): same-A blocks are
// dispatch-adjacent -> L2/L3 hits; ebf (134 MB) is L3-resident.
__global__ __launch_bounds__(256) void k_copyseq_bf(const unsigned short* ebf,
                                                    const unsigned short* Wcb,
                                                    const float* ao, float* logit) {
    __shared__ __align__(16) unsigned char smem[65536];
    unsigned char* const A0 = smem;
    unsigned char* const A1 = smem + 16384;
    unsigned char* const B0 = smem + 32768;
    unsigned char* const B1 = smem + 49152;
    const int n0 = blockIdx.x * 128;
    const int m0 = blockIdx.y * 128;
    const int b = blockIdx.y >> 2;  // 4 M-tiles per batch row (512/128)
    const int tid = threadIdx.x;
    const int w = tid >> 6, lane = tid & 63;
    const int wm = w >> 1, wn = w & 1, lq = lane >> 4, lr = lane & 15;
    const unsigned short* Asrc = ebf + (size_t)m0 * 512;
    const unsigned short* Bsrc = Wcb + (size_t)n0 * 512;

    f32x4 acc[4][4];
#pragma unroll
    for (int mi = 0; mi < 4; ++mi)
#pragma unroll
        for (int ni = 0; ni < 4; ++ni) acc[mi][ni] = f32x4{0.f, 0.f, 0.f, 0.f};

    stage_bf16_128(Asrc, 512, 0, A0);
    stage_bf16_128(Bsrc, 512, 0, B0);

    for (int kc = 0; kc < 8; ++kc) {
        __syncthreads();
        const unsigned char* Ac = (kc & 1) ? A1 : A0;
        const unsigned char* Bc = (kc & 1) ? B1 : B0;
        if (kc < 7) {
            stage_bf16_128(Asrc, 512, (kc + 1) * 64, (kc & 1) ? A0 : A1);
            stage_bf16_128(Bsrc, 512, (kc + 1) * 64, (kc & 1) ? B0 : B1);
        }
#pragma unroll
        for (int ks = 0; ks < 2; ++ks) {
            const int kb = ks * 64 + lq * 16;
            s16x8 afr[4], bfr[4];
#pragma unroll
            for (int mi = 0; mi < 4; ++mi) {
                const int ar = wm * 64 + mi * 16 + lr;
                afr[mi] = *(const s16x8*)(Ac + ar * 128 + (kb ^ ((ar & 7) << 4)));
            }
#pragma unroll
            for (int ni = 0; ni < 4; ++ni) {
                const int br = wn * 64 + ni * 16 + lr;
                bfr[ni] = *(const s16x8*)(Bc + br * 128 + (kb ^ ((br & 7) << 4)));
            }
#pragma unroll
            for (int mi = 0; mi < 4; ++mi)
#pragma unroll
                for (int ni = 0; ni < 4; ++ni) mfma_acc(acc[mi][ni], afr[mi], bfr[ni]);
        }
    }

    // epilogue: logit[s] += sum over this wave's 64 n-cols of tanh(P)*ao
    float aow[4];
#pragma unroll
    for (int ni = 0; ni < 4; ++ni) aow[ni] = ao[b * 512 + n0 + wn * 64 + ni * 16 + lr];
#pragma unroll
    for (int mi = 0; mi < 4; ++mi) {
#pragma unroll
        for (int r = 0; r < 4; ++r) {
            float p = 0.f;
#pragma unroll
            for (int ni = 0; ni < 4; ++ni) p += fast_tanh(acc[mi][ni][r]) * aow[ni];
            p += __shfl_xor(p, 1, 16);
            p += __shfl_xor(p, 2, 16);
            p += __shfl_xor(p, 4, 16);
            p += __shfl_xor(p, 8, 16);
            if (lr == 0)
                atomicAdd(&logit[(size_t)m0 + wm * 64 + mi * 16 + lq * 4 + r], p);
        }
    }
}

// Fallback (ws too small for ebf): round-3 version, f32 A reg-staged.
__global__ __launch_bounds__(256) void k_copyseq(const float* enc, const unsigned short* Wcb,
                                                 const float* ao, float* logit) {
    __shared__ __align__(16) unsigned char smem[65536];
    unsigned char* const A0 = smem;
    unsigned char* const A1 = smem + 16384;
    unsigned char* const B0 = smem + 32768;
    unsigned char* const B1 = smem + 49152;
    const int m0 = blockIdx.x * 128;
    const int n0 = blockIdx.y * 128;
    const int b = blockIdx.x >> 2;
    const int tid = threadIdx.x;
    const int w = tid >> 6, lane = tid & 63;
    const int wm = w >> 1, wn = w & 1, lq = lane >> 4, lr = lane & 15;
    const float* Asrc = enc + (size_t)m0 * 512;

    f32x4 acc[4][4];
#pragma unroll
    for (int mi = 0; mi < 4; ++mi)
#pragma unroll
        for (int ni = 0; ni < 4; ++ni) acc[mi][ni] = f32x4{0.f, 0.f, 0.f, 0.f};

    const int arow_t = tid >> 3, au_t = tid & 7;
    {
#pragma unroll
        for (int it = 0; it < 4; ++it) {
            const int row = arow_t + it * 32;
            const float* g = Asrc + (size_t)row * 512 + au_t * 8;
            const float4 v0 = *(const float4*)g;
            const float4 v1 = *(const float4*)(g + 4);
            uint4 pk;
            pk.x = (unsigned int)f2bf(v0.x) | ((unsigned int)f2bf(v0.y) << 16);
            pk.y = (unsigned int)f2bf(v0.z) | ((unsigned int)f2bf(v0.w) << 16);
            pk.z = (unsigned int)f2bf(v1.x) | ((unsigned int)f2bf(v1.y) << 16);
            pk.w = (unsigned int)f2bf(v1.z) | ((unsigned int)f2bf(v1.w) << 16);
            *(uint4*)(A0 + row * 128 + ((au_t * 16) ^ ((row & 7) << 4))) = pk;
        }
        stage_bf16_128(Wcb + (size_t)n0 * 512, 512, 0, B0);
    }

    for (int kc = 0; kc < 8; ++kc) {
        __syncthreads();
        const unsigned char* Ac = (kc & 1) ? A1 : A0;
        const unsigned char* Bc = (kc & 1) ? B1 : B0;
        unsigned char* An = (kc & 1) ? A0 : A1;
        unsigned char* Bn = (kc & 1) ? B0 : B1;
        float4 va[4], vb[4];
        if (kc < 7) {
            const int k0 = (kc + 1) * 64;
#pragma unroll
            for (int it = 0; it < 4; ++it) {
                const int row = arow_t + it * 32;
                const float* g = Asrc + (size_t)row * 512 + k0 + au_t * 8;
                va[it] = *(const float4*)g;
                vb[it] = *(const float4*)(g + 4);
            }
            stage_bf16_128(Wcb + (size_t)n0 * 512, 512, k0, Bn);
        }
#pragma unroll
        for (int ks = 0; ks < 2; ++ks) {
            const int kb = ks * 64 + lq * 16;
            s16x8 afr[4], bfr[4];
#pragma unroll
            for (int mi = 0; mi < 4; ++mi) {
                const int ar = wm * 64 + mi * 16 + lr;
                afr[mi] = *(const s16x8*)(Ac + ar * 128 + (kb ^ ((ar & 7) << 4)));
            }
#pragma unroll
            for (int ni = 0; ni < 4; ++ni) {
                const int br = wn * 64 + ni * 16 + lr;
                bfr[ni] = *(const s16x8*)(Bc + br * 128 + (kb ^ ((br & 7) << 4)));
            }
#pragma unroll
            for (int mi = 0; mi < 4; ++mi)
#pragma unroll
                for (int ni = 0; ni < 4; ++ni) mfma_acc(acc[mi][ni], afr[mi], bfr[ni]);
        }
        if (kc < 7) {
#pragma unroll
            for (int it = 0; it < 4; ++it) {
                const int row = arow_t + it * 32;
                uint4 pk;
                pk.x = (unsigned int)f2bf(va[it].x) | ((unsigned int)f2bf(va[it].y) << 16);
                pk.y = (unsigned int)f2bf(va[it].z) | ((unsigned int)f2bf(va[it].w) << 16);
                pk.z = (unsigned int)f2bf(vb[it].x) | ((unsigned int)f2bf(vb[it].y) << 16);
                pk.w = (unsigned int)f2bf(vb[it].z) | ((unsigned int)f2bf(vb[it].w) << 16);
                *(uint4*)(An + row * 128 + ((au_t * 16) ^ ((row & 7) << 4))) = pk;
            }
        }
    }

    float aow[4];
#pragma unroll
    for (int ni = 0; ni < 4; ++ni) aow[ni] = ao[b * 512 + n0 + wn * 64 + ni * 16 + lr];
#pragma unroll
    for (int mi = 0; mi < 4; ++mi) {
#pragma unroll
        for (int r = 0; r < 4; ++r) {
            float p = 0.f;
#pragma unroll
            for (int ni = 0; ni < 4; ++ni) p += fast_tanh(acc[mi][ni][r]) * aow[ni];
            p += __shfl_xor(p, 1, 16);
            p += __shfl_xor(p, 2, 16);
            p += __shfl_xor(p, 4, 16);
            p += __shfl_xor(p, 8, 16);
            if (lr == 0)
                atomicAdd(&logit[(size_t)m0 + wm * 64 + mi * 16 + lq * 4 + r], p);
        }
    }
}

__global__ __launch_bounds__(256) void k_scatter(const float* logit, const int* stok,
                                                 const void* maskp, const int* flagp,
                                                 float* out, float* rowsum) {
    const int idx = blockIdx.x * 256 + threadIdx.x;
    const int b = idx >> 9;
    const int flag = *flagp;
    float v = 0.f;
    if (!get_mask(maskp, flag, idx)) {
        v = __expf(logit[idx]);
        atomicAdd(&out[(size_t)b * VX_ + stok[idx]], v);
    }
    float s = v;
#pragma unroll
    for (int o = 1; o < 64; o <<= 1) s += __shfl_xor(s, o, 64);
    if ((threadIdx.x & 63) == 0) atomicAdd(&rowsum[b], s);
}

__global__ __launch_bounds__(256) void k_final(float* out, const float* rowsum) {
    const int b = blockIdx.y;
    const float ls = logf(rowsum[b]);
    int v = blockIdx.x * 1024 + threadIdx.x;
#pragma unroll
    for (int i = 0; i < 4; ++i, v += 256) {
        if (v < VX_) {
            const size_t o = (size_t)b * VX_ + v;
            out[o] = logf(out[o]) - ls;
        }
    }
}

// ---- host ------------------------------------------------------------------

extern "C" void kernel_launch(void* const* d_in, const int* in_sizes, int n_in, void* d_out,
                              int out_size, void* d_ws, size_t ws_size, hipStream_t stream) {
    const float* embedding = (const float*)d_in[0];
    const float* W_ih = (const float*)d_in[1];
    const float* W_hh = (const float*)d_in[2];
    const float* b_ih = (const float*)d_in[3];
    const float* b_hh = (const float*)d_in[4];
    const float* W_attn = (const float*)d_in[5];
    const float* W_out = (const float*)d_in[6];
    const float* b_out = (const float*)d_in[7];
    const float* W_copy = (const float*)d_in[8];
    // d_in[9] = W_incopy: provably dead in the reference (tanh(0)=0 on unmatched,
    // matched positions masked to -inf => softmax is uniform over unmatched).
    const float* W_gen = (const float*)d_in[10];
    const float* enc = (const float*)d_in[11];
    const float* pcs = (const float*)d_in[12];
    const float* h0 = (const float*)d_in[13];
    const float* c0 = (const float*)d_in[14];
    const int* ptok = (const int*)d_in[15];
    const int* stok = (const int*)d_in[16];
    const void* maskp = d_in[17];
    float* out = (float*)d_out;

    char* ws = (char*)d_ws;
    size_t off = 0;
    auto alloc = [&](size_t bytes) {
        size_t o = off;
        off += (bytes + 255) & ~(size_t)255;
        return o;
    };
    int* flag = (int*)(ws + alloc(4));
    float* rowsum = (float*)(ws + alloc(B_ * 4));
    float* cs_sum = (float*)(ws + alloc((size_t)1024 * SRC_ * 4));
    int* cs_cnt = (int*)(ws + alloc(1024 * 4));
    unsigned short* xh = (unsigned short*)(ws + alloc((size_t)B_ * KXH * 2));
    unsigned short* Wg = (unsigned short*)(ws + alloc((size_t)2048 * KXH * 2));
    unsigned short* Wcb = (unsigned short*)(ws + alloc((size_t)512 * 512 * 2));
    float* gates = (float*)(ws + alloc((size_t)B_ * 2048 * 4));
    unsigned short* h1b = (unsigned short*)(ws + alloc((size_t)B_ * 512 * 2));
    float* qbuf = (float*)(ws + alloc((size_t)B_ * 512 * 4));
    float* parts = (float*)(ws + alloc((size_t)4 * B_ * 512 * 4));
    float* md = (float*)(ws + alloc((size_t)4 * B_ * 2 * 4));
    unsigned short* ch = (unsigned short*)(ws + alloc((size_t)B_ * 1024 * 2));
    unsigned short* aob = (unsigned short*)(ws + alloc((size_t)B_ * 512 * 2));
    float* logit = (float*)(ws + alloc((size_t)B_ * S_ * 4));
    const size_t ebf_bytes = (size_t)B_ * S_ * SRC_ * 2;  // 134 MB
    const int use_ebf = (off + ebf_bytes <= ws_size) ? 1 : 0;
    unsigned short* ebf = (unsigned short*)(ws + off);
    (void)n_in; (void)in_sizes; (void)out_size;

    hipLaunchKernelGGL(k_zero, dim3(513), dim3(256), 0, stream, logit, flag, rowsum);
    hipLaunchKernelGGL(k_scan, dim3(64), dim3(256), 0, stream, maskp, flag);
    hipLaunchKernelGGL(k_cs_part, dim3(1024), dim3(256), 0, stream, enc, stok, ptok, cs_sum,
                       cs_cnt, ebf, use_ebf);
    hipLaunchKernelGGL(k_wcvt, dim3(4096), dim3(256), 0, stream, W_ih, W_hh, W_copy, Wg, Wcb);
    hipLaunchKernelGGL(k_cs_final, dim3(256), dim3(256), 0, stream, cs_sum, cs_cnt, embedding,
                       ptok, pcs, h0, xh);
    hipLaunchKernelGGL(k_gates, dim3(4, 32), dim3(256), 0, stream, xh, Wg, b_ih, b_hh, gates);
    hipLaunchKernelGGL(k_lstm, dim3(512), dim3(256), 0, stream, gates, c0, out, h1b);
    hipLaunchKernelGGL(k_q, dim3(4, 8), dim3(256), 0, stream, h1b, W_attn, qbuf);
    hipLaunchKernelGGL(k_attn, dim3(4, 256), dim3(256), 0, stream, enc, ebf, use_ebf, qbuf,
                       maskp, flag, parts, md);
    hipLaunchKernelGGL(k_attn_merge, dim3(256), dim3(256), 0, stream, parts, md, h1b, ch);
    hipLaunchKernelGGL(k_attnout, dim3(4, 8), dim3(256), 0, stream, ch, W_out, b_out, out, aob);
    hipLaunchKernelGGL(k_gen, dim3(4, 782), dim3(256), 0, stream, aob, W_gen, out, rowsum);
    hipLaunchKernelGGL(k_oov, dim3(100), dim3(256), 0, stream, out);
    if (use_ebf) {
        hipLaunchKernelGGL(k_copyseq_bf, dim3(4, 1024), dim3(256), 0, stream, ebf, Wcb,
                           out + ATT_OFF, logit);
    } else {
        hipLaunchKernelGGL(k_copyseq, dim3(1024, 4), dim3(256), 0, stream, enc, Wcb,
                           out + ATT_OFF, logit);
    }
    hipLaunchKernelGGL(k_scatter, dim3(512), dim3(256), 0, stream, logit, stok, maskp, flag,
                       out, rowsum);
    hipLaunchKernelGGL(k_final, dim3(49, 256), dim3(256), 0, stream, out, rowsum);
}

// Round 5
// 512.288 us; speedup vs baseline: 1.4258x; 1.0101x over previous
//
#include <hip/hip_runtime.h>
#include <math.h>

#define V_ 50000
#define OOV_ 100
#define VX_ 50100
#define B_ 256
#define S_ 512
#define TH_ 512
#define SRC_ 512
#define KXH 1664

#define ATT_OFF ((size_t)B_ * VX_)
#define H1_OFF (ATT_OFF + (size_t)B_ * TH_)
#define C1_OFF (H1_OFF + (size_t)B_ * TH_)

typedef float f32x4 __attribute__((ext_vector_type(4)));
typedef short s16x8 __attribute__((ext_vector_type(8)));

__device__ __forceinline__ unsigned short f2bf(float f) {
    unsigned int u = __float_as_uint(f);
    u += 0x7FFFu + ((u >> 16) & 1u);
    return (unsigned short)(u >> 16);
}
__device__ __forceinline__ float fast_tanh(float x) {
    return 1.0f - 2.0f / (__expf(2.0f * x) + 1.0f);
}
__device__ __forceinline__ float sigm(float x) { return 1.0f / (1.0f + __expf(-x)); }

__device__ __forceinline__ bool get_mask(const void* m, int flag, size_t idx) {
    return flag ? (((const unsigned char*)m)[idx] != 0)
                : (((const int*)m)[idx] != 0);
}

// Builtin MFMA: compiler models MFMA->VALU hazards (inline-asm version corrupted
// accumulators -- round 1->2 lesson).
__device__ __forceinline__ void mfma_acc(f32x4& c, s16x8 a, s16x8 b) {
    c = __builtin_amdgcn_mfma_f32_16x16x32_bf16(a, b, c, 0, 0, 0);
}

// ---- staging helpers -------------------------------------------------------
// LDS tile layout: [rows][128 bytes], swizzle: byte ^= ((row&7)<<4)

__device__ __forceinline__ void stage_bf16(const unsigned short* src, int ld,
                                           int row0, int k0, unsigned char* ldsbase) {
    const int tid = threadIdx.x;
    const int w = tid >> 6, lane = tid & 63;
#pragma unroll
    for (int jj = 0; jj < 2; ++jj) {
        const int qq = w * 2 + jj;               // 0..7, wave-uniform
        const int rowl = qq * 8 + (lane >> 3);
        const int su = (lane & 7) ^ (rowl & 7);  // pre-swizzled global source
        const unsigned short* g = src + (size_t)(row0 + rowl) * ld + k0 + su * 8;
        __builtin_amdgcn_global_load_lds(
            (const __attribute__((address_space(1))) void*)g,
            (__attribute__((address_space(3))) void*)(ldsbase + qq * 1024), 16, 0, 0);
    }
}

// 128-row variant (16 KB tile), same layout/swizzle
__device__ __forceinline__ void stage_bf16_128(const unsigned short* src, int ld,
                                               int k0, unsigned char* ldsbase) {
    const int tid = threadIdx.x;
    const int w = tid >> 6, lane = tid & 63;
#pragma unroll
    for (int jj = 0; jj < 4; ++jj) {
        const int qq = w * 4 + jj;               // 0..15, wave-uniform
        const int rowl = qq * 8 + (lane >> 3);   // 0..127
        const int su = (lane & 7) ^ (rowl & 7);
        const unsigned short* g = src + (size_t)rowl * ld + k0 + su * 8;
        __builtin_amdgcn_global_load_lds(
            (const __attribute__((address_space(1))) void*)g,
            (__attribute__((address_space(3))) void*)(ldsbase + qq * 1024), 16, 0, 0);
    }
}

__device__ __forceinline__ void stage_f32(const float* src, int ld, int row0, int k0,
                                          int rowmax, unsigned char* ldsbase) {
    const int tid = threadIdx.x;
#pragma unroll
    for (int it = 0; it < 4; ++it) {
        const int p = it * 256 + tid;
        const int row = p >> 4;
        const int u4 = p & 15;
        int gr = row0 + row;
        gr = gr > rowmax ? rowmax : gr;
        const float4 v = *(const float4*)(src + (size_t)gr * ld + k0 + u4 * 4);
        unsigned int lo = (unsigned int)f2bf(v.x) | ((unsigned int)f2bf(v.y) << 16);
        unsigned int hi = (unsigned int)f2bf(v.z) | ((unsigned int)f2bf(v.w) << 16);
        *(uint2*)(ldsbase + row * 128 + ((u4 * 8) ^ ((row & 7) << 4))) = make_uint2(lo, hi);
    }
}

__device__ __forceinline__ void compute64(const unsigned char* Ab, const unsigned char* Bb,
                                          f32x4 acc[4]) {
    const int tid = threadIdx.x;
    const int w = tid >> 6, lane = tid & 63, lq = lane >> 4, lr = lane & 15;
#pragma unroll
    for (int ks = 0; ks < 2; ++ks) {
        const int kb = ks * 64 + lq * 16;
        const int ar = w * 16 + lr;
        s16x8 a = *(const s16x8*)(Ab + ar * 128 + (kb ^ ((ar & 7) << 4)));
#pragma unroll
        for (int ns = 0; ns < 4; ++ns) {
            const int br = ns * 16 + lr;
            s16x8 b = *(const s16x8*)(Bb + br * 128 + (kb ^ ((br & 7) << 4)));
            mfma_acc(acc[ns], a, b);
        }
    }
}

// Generic 64x64-tile GEMM core: C = A(bf16, MxK row-major) * B^T (B is NxK row-major)
template <bool BF32>
__device__ __forceinline__ void gemm_main(const unsigned short* A, int lda, const void* Bp,
                                          int ldb, int nkc, int kbase, int rowmaxB, int m0,
                                          int n0, unsigned char* smem, f32x4 acc[4]) {
#pragma unroll
    for (int i = 0; i < 4; ++i) acc[i] = f32x4{0.f, 0.f, 0.f, 0.f};
    unsigned char* const A0 = smem;
    unsigned char* const A1 = smem + 8192;
    unsigned char* const B0 = smem + 16384;
    unsigned char* const B1 = smem + 24576;
    stage_bf16(A, lda, m0, kbase, A0);
    if (BF32) stage_f32((const float*)Bp, ldb, n0, kbase, rowmaxB, B0);
    else      stage_bf16((const unsigned short*)Bp, ldb, n0, kbase, B0);
    int cur = 0;
    for (int kc = 0; kc < nkc; ++kc) {
        __syncthreads();
        if (kc + 1 < nkc) {
            const int k0 = kbase + (kc + 1) * 64;
            stage_bf16(A, lda, m0, k0, cur ? A0 : A1);
            if (BF32) stage_f32((const float*)Bp, ldb, n0, k0, rowmaxB, cur ? B0 : B1);
            else      stage_bf16((const unsigned short*)Bp, ldb, n0, k0, cur ? B0 : B1);
        }
        compute64(cur ? A1 : A0, cur ? B1 : B0, acc);
        cur ^= 1;
    }
}

// ---- kernels ---------------------------------------------------------------

// Fused prelude: all mutually-independent setup work in ONE launch.
// blocks [0,1024)        : cs_part (copy_state partial means + ebf materialize)
// blocks [1024,1536)     : zero logit
// block  1536            : rowsum init (OOV count)
// block  1537            : mask layout scan -> flag
// blocks [1538,1638)     : OOV base 1.0 into out
// blocks [1638,2150)     : weight f32->bf16 convert (vectorized)
// blocks [2150,2662)     : zero gates (for split-K atomics)
__global__ __launch_bounds__(256) void k_pre(const float* enc, const int* stok, const int* ptok,
                                             float* cs_sum, int* cs_cnt, unsigned short* ebf,
                                             int do_cvt, float* logit, float* rowsum,
                                             const void* maskp, int* flag, float* out,
                                             const float* W_ih, const float* W_hh,
                                             const float* W_copy, unsigned short* Wg,
                                             unsigned short* Wcb, float* gates) {
    const int bid = blockIdx.x, tid = threadIdx.x;
    if (bid < 1024) {
        __shared__ float comb[512];
        __shared__ int cc[2];
        const int b = bid >> 2, chunk = bid & 3;
        const int h = tid >> 7, d0 = (tid & 127) * 4;
        const int prev = ptok[b];
        const float* base = enc + ((size_t)b * S_ + chunk * 128) * SRC_;
        const int* st = stok + b * S_ + chunk * 128;
        unsigned short* eb = ebf + ((size_t)b * S_ + chunk * 128) * SRC_;
        float a0 = 0.f, a1 = 0.f, a2 = 0.f, a3 = 0.f;
        int cnt = 0;
        for (int s2 = 0; s2 < 64; ++s2) {
            const int s = s2 * 2 + h;
            const float4 v = *(const float4*)(base + (size_t)s * SRC_ + d0);
            if (st[s] != prev) { a0 += v.x; a1 += v.y; a2 += v.z; a3 += v.w; ++cnt; }
            if (do_cvt) {
                uint2 pk;
                pk.x = (unsigned int)f2bf(v.x) | ((unsigned int)f2bf(v.y) << 16);
                pk.y = (unsigned int)f2bf(v.z) | ((unsigned int)f2bf(v.w) << 16);
                *(uint2*)(eb + (size_t)s * SRC_ + d0) = pk;
            }
        }
        if (h == 0) {
            comb[d0] = a0; comb[d0 + 1] = a1; comb[d0 + 2] = a2; comb[d0 + 3] = a3;
            if (tid == 0) cc[0] = cnt;
        }
        __syncthreads();
        if (h == 1) {
            comb[d0] += a0; comb[d0 + 1] += a1; comb[d0 + 2] += a2; comb[d0 + 3] += a3;
            if (tid == 128) cc[1] = cnt;
        }
        __syncthreads();
        cs_sum[(size_t)bid * SRC_ + tid] = comb[tid];
        cs_sum[(size_t)bid * SRC_ + 256 + tid] = comb[256 + tid];
        if (tid == 0) cs_cnt[bid] = cc[0] + cc[1];
    } else if (bid < 1536) {
        logit[(bid - 1024) * 256 + tid] = 0.f;
    } else if (bid == 1536) {
        rowsum[tid] = (float)OOV_;
    } else if (bid == 1537) {
        __shared__ int sfl;
        if (tid == 0) sfl = 0;
        __syncthreads();
        const uint4* m4 = (const uint4*)maskp;
        unsigned int ev = 0;
        for (int i = tid; i < (B_ * S_) / 16; i += 256) {
            const uint4 u = m4[i];
            ev |= (u.x | u.y | u.z | u.w) & 0xFFFFFF00u;
        }
        if (ev) atomicOr(&sfl, 1);
        __syncthreads();
        if (tid == 0) *flag = sfl;   // 1 => bool(1B) layout, 0 => int32 layout
    } else if (bid < 1638) {
        const int p = (bid - 1538) * 256 + tid;
        if (p < B_ * OOV_) {
            const int b = p / OOV_, j = p - b * OOV_;
            out[(size_t)b * VX_ + V_ + j] = 1.0f;   // exp(0) base for OOV columns
        }
    } else if (bid < 2150) {
        const int NWG = 2048 * KXH;
        const int NTOT4 = (NWG + 512 * 512) / 4;
        for (int i4 = (bid - 1638) * 256 + tid; i4 < NTOT4; i4 += 512 * 256) {
            const int e = i4 * 4;
            float4 v;
            unsigned short* dst;
            if (e < NWG) {
                const int r = e / KXH, c = e - r * KXH;
                v = (c < 1152) ? *(const float4*)(W_ih + (size_t)r * 1152 + c)
                               : *(const float4*)(W_hh + (size_t)r * 512 + (c - 1152));
                dst = Wg + e;
            } else {
                v = *(const float4*)(W_copy + (e - NWG));
                dst = Wcb + (e - NWG);
            }
            uint2 pk;
            pk.x = (unsigned int)f2bf(v.x) | ((unsigned int)f2bf(v.y) << 16);
            pk.y = (unsigned int)f2bf(v.z) | ((unsigned int)f2bf(v.w) << 16);
            *(uint2*)dst = pk;
        }
    } else {
        ((float4*)gates)[(bid - 2150) * 256 + tid] = make_float4(0.f, 0.f, 0.f, 0.f);
    }
}

__global__ __launch_bounds__(256) void k_cs_final(const float* cs_sum, const int* cs_cnt,
                                                  const float* embedding, const int* ptok,
                                                  const float* pcs, const float* h0,
                                                  unsigned short* xh) {
    const int b = blockIdx.x, tid = threadIdx.x;
    const int cnt = cs_cnt[b * 4] + cs_cnt[b * 4 + 1] + cs_cnt[b * 4 + 2] + cs_cnt[b * 4 + 3];
    const float inv = 1.f / (float)cnt;
    unsigned short* row = xh + (size_t)b * KXH;
    for (int d = tid; d < 512; d += 256) {
        float s = cs_sum[(size_t)(b * 4 + 0) * SRC_ + d] + cs_sum[(size_t)(b * 4 + 1) * SRC_ + d] +
                  cs_sum[(size_t)(b * 4 + 2) * SRC_ + d] + cs_sum[(size_t)(b * 4 + 3) * SRC_ + d];
        row[640 + d] = f2bf(s * inv);              // copy_state
        row[128 + d] = f2bf(pcs[b * 512 + d]);     // prev_context_state
        row[1152 + d] = f2bf(h0[b * 512 + d]);     // h0 (for W_hh part)
    }
    if (tid < 128) {
        int tk = ptok[b];
        if (tk >= V_) tk = 1;  // UNK
        row[tid] = f2bf(embedding[(size_t)tk * 128 + tid]);
    }
}

// split-K=2: each half atomicAdds into zero-initialized gates. Exactly 2
// commutative float adds per element onto exact 0 -> deterministic.
__global__ __launch_bounds__(256) void k_gates(const unsigned short* xh, const unsigned short* Wg,
                                               float* gates) {
    __shared__ __align__(16) unsigned char smem[32768];
    f32x4 acc[4];
    const int m0 = blockIdx.x * 64, n0 = blockIdx.y * 64;
    const int kb = blockIdx.z ? 832 : 0;
    gemm_main<false>(xh, KXH, Wg, KXH, 13, kb, 2047, m0, n0, smem, acc);
    const int tid = threadIdx.x, w = tid >> 6, lane = tid & 63, lq = lane >> 4, lr = lane & 15;
#pragma unroll
    for (int ns = 0; ns < 4; ++ns) {
        const int n = n0 + ns * 16 + lr;
#pragma unroll
        for (int r = 0; r < 4; ++r) {
            const int m = m0 + w * 16 + lq * 4 + r;
            atomicAdd(&gates[(size_t)m * 2048 + n], acc[ns][r]);
        }
    }
}

__global__ __launch_bounds__(256) void k_lstm(const float* gates, const float* b_ih,
                                              const float* b_hh, const float* c0, float* out,
                                              unsigned short* h1b) {
    const int idx = blockIdx.x * 256 + threadIdx.x;  // 0..131071
    const int b = idx >> 9, h = idx & 511;
    const float gi = gates[(size_t)b * 2048 + h] + b_ih[h] + b_hh[h];
    const float gf = gates[(size_t)b * 2048 + 512 + h] + b_ih[512 + h] + b_hh[512 + h];
    const float gg = gates[(size_t)b * 2048 + 1024 + h] + b_ih[1024 + h] + b_hh[1024 + h];
    const float go = gates[(size_t)b * 2048 + 1536 + h] + b_ih[1536 + h] + b_hh[1536 + h];
    const float c1 = sigm(gf) * c0[idx] + sigm(gi) * fast_tanh(gg);
    const float h1 = sigm(go) * fast_tanh(c1);
    out[H1_OFF + idx] = h1;
    out[C1_OFF + idx] = c1;
    h1b[idx] = f2bf(h1);
}

__global__ __launch_bounds__(256) void k_q(const unsigned short* h1b, const float* W_attn,
                                           float* qbuf) {
    __shared__ __align__(16) unsigned char smem[32768];
    f32x4 acc[4];
    const int m0 = blockIdx.x * 64, n0 = blockIdx.y * 64;
    gemm_main<true>(h1b, 512, W_attn, 512, 8, 0, 511, m0, n0, smem, acc);
    const int tid = threadIdx.x, w = tid >> 6, lane = tid & 63, lq = lane >> 4, lr = lane & 15;
#pragma unroll
    for (int ns = 0; ns < 4; ++ns) {
        const int n = n0 + ns * 16 + lr;
#pragma unroll
        for (int r = 0; r < 4; ++r)
            qbuf[(size_t)(m0 + w * 16 + lq * 4 + r) * 512 + n] = acc[ns][r];
    }
}

// Register-resident GEMV attention with online softmax. One wave owns 32 s-rows;
// q in 8 regs/lane; one 16B load per row; masked rows skipped (load + compute).
__global__ __launch_bounds__(256) void k_attn2(const float* enc, const unsigned short* ebf,
                                               const int use_ebf, const float* qv,
                                               const void* maskp, const int* flagp,
                                               float* parts, float* md) {
    const int chunk = blockIdx.x, b = blockIdx.y;
    const int tid = threadIdx.x, w = tid >> 6, lane = tid & 63;
    const int flag = *flagp;
    float q0[8];
    {
        const float4 t0 = *(const float4*)(qv + b * 512 + lane * 8);
        const float4 t1 = *(const float4*)(qv + b * 512 + lane * 8 + 4);
        q0[0] = t0.x; q0[1] = t0.y; q0[2] = t0.z; q0[3] = t0.w;
        q0[4] = t1.x; q0[5] = t1.y; q0[6] = t1.z; q0[7] = t1.w;
    }
    float M = -INFINITY, den = 0.f;
    float cv[8] = {0.f, 0.f, 0.f, 0.f, 0.f, 0.f, 0.f, 0.f};
    const int s0 = chunk * 128 + w * 32;
    for (int i = 0; i < 32; ++i) {
        const int s = s0 + i;
        if (get_mask(maskp, flag, (size_t)b * S_ + s)) continue;  // wave-uniform
        float v[8];
        if (use_ebf) {
            const uint4 u = *(const uint4*)(ebf + ((size_t)b * S_ + s) * 512 + lane * 8);
            v[0] = __uint_as_float(u.x << 16);
            v[1] = __uint_as_float(u.x & 0xffff0000u);
            v[2] = __uint_as_float(u.y << 16);
            v[3] = __uint_as_float(u.y & 0xffff0000u);
            v[4] = __uint_as_float(u.z << 16);
            v[5] = __uint_as_float(u.z & 0xffff0000u);
            v[6] = __uint_as_float(u.w << 16);
            v[7] = __uint_as_float(u.w & 0xffff0000u);
        } else {
            const float4 t0 = *(const float4*)(enc + ((size_t)b * S_ + s) * 512 + lane * 8);
            const float4 t1 = *(const float4*)(enc + ((size_t)b * S_ + s) * 512 + lane * 8 + 4);
            v[0] = t0.x; v[1] = t0.y; v[2] = t0.z; v[3] = t0.w;
            v[4] = t1.x; v[5] = t1.y; v[6] = t1.z; v[7] = t1.w;
        }
        float a = 0.f;
#pragma unroll
        for (int j = 0; j < 8; ++j) a += q0[j] * v[j];
        a += __shfl_xor(a, 1);
        a += __shfl_xor(a, 2);
        a += __shfl_xor(a, 4);
        a += __shfl_xor(a, 8);
        a += __shfl_xor(a, 16);
        a += __shfl_xor(a, 32);
        const float nM = fmaxf(M, a);
        const float sc = __expf(M - nM);   // M=-inf -> 0
        const float p = __expf(a - nM);
        den = den * sc + p;
#pragma unroll
        for (int j = 0; j < 8; ++j) cv[j] = cv[j] * sc + p * v[j];
        M = nM;
    }
    const int part = chunk * 4 + w;
    float* pp = parts + ((size_t)part * B_ + b) * 512 + lane * 8;
    *(float4*)pp = make_float4(cv[0], cv[1], cv[2], cv[3]);
    *(float4*)(pp + 4) = make_float4(cv[4], cv[5], cv[6], cv[7]);
    if (lane == 0) {
        md[(part * B_ + b) * 2] = M;
        md[(part * B_ + b) * 2 + 1] = den;
    }
}

__global__ __launch_bounds__(256) void k_merge16(const float* parts, const float* md,
                                                 const unsigned short* h1b, unsigned short* ch) {
    const int b = blockIdx.x, tid = threadIdx.x;
    float Ms[16], Ds[16], M = -INFINITY;
#pragma unroll
    for (int jj = 0; jj < 16; ++jj) {
        Ms[jj] = md[(jj * B_ + b) * 2];
        Ds[jj] = md[(jj * B_ + b) * 2 + 1];
        M = fmaxf(M, Ms[jj]);
    }
    float den = 0.f, sc[16];
#pragma unroll
    for (int jj = 0; jj < 16; ++jj) {
        sc[jj] = __expf(Ms[jj] - M);  // -inf -> 0
        den += Ds[jj] * sc[jj];
    }
    const float inv = 1.f / den;
    for (int d = tid; d < 512; d += 256) {
        float c = 0.f;
#pragma unroll
        for (int jj = 0; jj < 16; ++jj) c += parts[((size_t)jj * B_ + b) * 512 + d] * sc[jj];
        ch[(size_t)b * 1024 + d] = f2bf(c * inv);
    }
    ch[(size_t)b * 1024 + 512 + tid] = h1b[b * 512 + tid];
    ch[(size_t)b * 1024 + 512 + 256 + tid] = h1b[b * 512 + 256 + tid];
}

__global__ __launch_bounds__(256) void k_attnout(const unsigned short* ch, const float* W_out,
                                                 const float* b_out, float* out,
                                                 unsigned short* aob) {
    __shared__ __align__(16) unsigned char smem[32768];
    f32x4 acc[4];
    const int m0 = blockIdx.x * 64, n0 = blockIdx.y * 64;
    gemm_main<true>(ch, 1024, W_out, 1024, 16, 0, 511, m0, n0, smem, acc);
    const int tid = threadIdx.x, w = tid >> 6, lane = tid & 63, lq = lane >> 4, lr = lane & 15;
#pragma unroll
    for (int ns = 0; ns < 4; ++ns) {
        const int n = n0 + ns * 16 + lr;
        const float bb = b_out[n];
#pragma unroll
        for (int r = 0; r < 4; ++r) {
            const int m = m0 + w * 16 + lq * 4 + r;
            const float t = fast_tanh(acc[ns][r] + bb);
            out[ATT_OFF + (size_t)m * 512 + n] = t;
            aob[(size_t)m * 512 + n] = f2bf(t);
        }
    }
}

__global__ __launch_bounds__(256) void k_gen(const unsigned short* aob, const float* W_gen,
                                             float* out, float* rowsum) {
    __shared__ __align__(16) unsigned char smem[32768];
    f32x4 acc[4];
    const int m0 = blockIdx.x * 64, n0 = blockIdx.y * 64;
    gemm_main<true>(aob, 512, W_gen, 512, 8, 0, V_ - 1, m0, n0, smem, acc);
    const int tid = threadIdx.x, w = tid >> 6, lane = tid & 63, lq = lane >> 4, lr = lane & 15;
    float rp[4] = {0.f, 0.f, 0.f, 0.f};
#pragma unroll
    for (int ns = 0; ns < 4; ++ns) {
        const int n = n0 + ns * 16 + lr;
        if (n < V_) {
#pragma unroll
            for (int r = 0; r < 4; ++r) {
                const float v = __expf(acc[ns][r]);
                out[(size_t)(m0 + w * 16 + lq * 4 + r) * VX_ + n] = v;
                rp[r] += v;
            }
        }
    }
#pragma unroll
    for (int r = 0; r < 4; ++r) {
        rp[r] += __shfl_xor(rp[r], 1, 16);
        rp[r] += __shfl_xor(rp[r], 2, 16);
        rp[r] += __shfl_xor(rp[r], 4, 16);
        rp[r] += __shfl_xor(rp[r], 8, 16);
    }
    if (lr == 0) {
#pragma unroll
        for (int r = 0; r < 4; ++r) atomicAdd(&rowsum[m0 + w * 16 + lq * 4 + r], rp[r]);
    }
}

// copy_seq GEMM: A from bf16 enc (ebf) via global_load_lds. Grid (n=4, m=1024):
// same-A blocks dispatch-adjacent -> L2 hits. Fully-masked tiles early-exit
// (mask is monotone per row: arange >= length).
__global__ __launch_bounds__(256) void k_copyseq_bf(const unsigned short* ebf,
                                                    const unsigned short* Wcb,
                                                    const float* ao, const void* maskp,
                                                    const int* flagp, float* logit) {
    const int n0 = blockIdx.x * 128;
    const int m0 = blockIdx.y * 128;
    const int b = blockIdx.y >> 2;  // 4 M-tiles per batch row (512/128)
    if (get_mask(maskp, *flagp, (size_t)b * S_ + (m0 & 511))) return;  // whole tile masked
    __shared__ __align__(16) unsigned char smem[65536];
    unsigned char* const A0 = smem;
    unsigned char* const A1 = smem + 16384;
    unsigned char* const B0 = smem + 32768;
    unsigned char* const B1 = smem + 49152;
    const int tid = threadIdx.x;
    const int w = tid >> 6, lane = tid & 63;
    const int wm = w >> 1, wn = w & 1, lq = lane >> 4, lr = lane & 15;
    const unsigned short* Asrc = ebf + (size_t)m0 * 512;
    const unsigned short* Bsrc = Wcb + (size_t)n0 * 512;

    f32x4 acc[4][4];
#pragma unroll
    for (int mi = 0; mi < 4; ++mi)
#pragma unroll
        for (int ni = 0; ni < 4; ++ni) acc[mi][ni] = f32x4{0.f, 0.f, 0.f, 0.f};

    stage_bf16_128(Asrc, 512, 0, A0);
    stage_bf16_128(Bsrc, 512, 0, B0);

    for (int kc = 0; kc < 8; ++kc) {
        __syncthreads();
        const unsigned char* Ac = (kc & 1) ? A1 : A0;
        const unsigned char* Bc = (kc & 1) ? B1 : B0;
        if (kc < 7) {
            stage_bf16_128(Asrc, 512, (kc + 1) * 64, (kc & 1) ? A0 : A1);
            stage_bf16_128(Bsrc, 512, (kc + 1) * 64, (kc & 1) ? B0 : B1);
        }
#pragma unroll
        for (int ks = 0; ks < 2; ++ks) {
            const int kb = ks * 64 + lq * 16;
            s16x8 afr[4], bfr[4];
#pragma unroll
            for (int mi = 0; mi < 4; ++mi) {
                const int ar = wm * 64 + mi * 16 + lr;
                afr[mi] = *(const s16x8*)(Ac + ar * 128 + (kb ^ ((ar & 7) << 4)));
            }
#pragma unroll
            for (int ni = 0; ni < 4; ++ni) {
                const int br = wn * 64 + ni * 16 + lr;
                bfr[ni] = *(const s16x8*)(Bc + br * 128 + (kb ^ ((br & 7) << 4)));
            }
#pragma unroll
            for (int mi = 0; mi < 4; ++mi)
#pragma unroll
                for (int ni = 0; ni < 4; ++ni) mfma_acc(acc[mi][ni], afr[mi], bfr[ni]);
        }
    }

    // epilogue: logit[s] += sum over this wave's 64 n-cols of tanh(P)*ao
    float aow[4];
#pragma unroll
    for (int ni = 0; ni < 4; ++ni) aow[ni] = ao[b * 512 + n0 + wn * 64 + ni * 16 + lr];
#pragma unroll
    for (int mi = 0; mi < 4; ++mi) {
#pragma unroll
        for (int r = 0; r < 4; ++r) {
            float p = 0.f;
#pragma unroll
            for (int ni = 0; ni < 4; ++ni) p += fast_tanh(acc[mi][ni][r]) * aow[ni];
            p += __shfl_xor(p, 1, 16);
            p += __shfl_xor(p, 2, 16);
            p += __shfl_xor(p, 4, 16);
            p += __shfl_xor(p, 8, 16);
            if (lr == 0)
                atomicAdd(&logit[(size_t)m0 + wm * 64 + mi * 16 + lq * 4 + r], p);
        }
    }
}

// Fallback (ws too small for ebf): f32 A reg-staged.
__global__ __launch_bounds__(256) void k_copyseq(const float* enc, const unsigned short* Wcb,
                                                 const float* ao, const void* maskp,
                                                 const int* flagp, float* logit) {
    const int m0 = blockIdx.x * 128;
    const int n0 = blockIdx.y * 128;
    const int b = blockIdx.x >> 2;
    if (get_mask(maskp, *flagp, (size_t)b * S_ + (m0 & 511))) return;
    __shared__ __align__(16) unsigned char smem[65536];
    unsigned char* const A0 = smem;
    unsigned char* const A1 = smem + 16384;
    unsigned char* const B0 = smem + 32768;
    unsigned char* const B1 = smem + 49152;
    const int tid = threadIdx.x;
    const int w = tid >> 6, lane = tid & 63;
    const int wm = w >> 1, wn = w & 1, lq = lane >> 4, lr = lane & 15;
    const float* Asrc = enc + (size_t)m0 * 512;

    f32x4 acc[4][4];
#pragma unroll
    for (int mi = 0; mi < 4; ++mi)
#pragma unroll
        for (int ni = 0; ni < 4; ++ni) acc[mi][ni] = f32x4{0.f, 0.f, 0.f, 0.f};

    const int arow_t = tid >> 3, au_t = tid & 7;
    {
#pragma unroll
        for (int it = 0; it < 4; ++it) {
            const int row = arow_t + it * 32;
            const float* g = Asrc + (size_t)row * 512 + au_t * 8;
            const float4 v0 = *(const float4*)g;
            const float4 v1 = *(const float4*)(g + 4);
            uint4 pk;
            pk.x = (unsigned int)f2bf(v0.x) | ((unsigned int)f2bf(v0.y) << 16);
            pk.y = (unsigned int)f2bf(v0.z) | ((unsigned int)f2bf(v0.w) << 16);
            pk.z = (unsigned int)f2bf(v1.x) | ((unsigned int)f2bf(v1.y) << 16);
            pk.w = (unsigned int)f2bf(v1.z) | ((unsigned int)f2bf(v1.w) << 16);
            *(uint4*)(A0 + row * 128 + ((au_t * 16) ^ ((row & 7) << 4))) = pk;
        }
        stage_bf16_128(Wcb + (size_t)n0 * 512, 512, 0, B0);
    }

    for (int kc = 0; kc < 8; ++kc) {
        __syncthreads();
        const unsigned char* Ac = (kc & 1) ? A1 : A0;
        const unsigned char* Bc = (kc & 1) ? B1 : B0;
        unsigned char* An = (kc & 1) ? A0 : A1;
        unsigned char* Bn = (kc & 1) ? B0 : B1;
        float4 va[4], vb[4];
        if (kc < 7) {
            const int k0 = (kc + 1) * 64;
#pragma unroll
            for (int it = 0; it < 4; ++it) {
                const int row = arow_t + it * 32;
                const float* g = Asrc + (size_t)row * 512 + k0 + au_t * 8;
                va[it] = *(const float4*)g;
                vb[it] = *(const float4*)(g + 4);
            }
            stage_bf16_128(Wcb + (size_t)n0 * 512, 512, k0, Bn);
        }
#pragma unroll
        for (int ks = 0; ks < 2; ++ks) {
            const int kb = ks * 64 + lq * 16;
            s16x8 afr[4], bfr[4];
#pragma unroll
            for (int mi = 0; mi < 4; ++mi) {
                const int ar = wm * 64 + mi * 16 + lr;
                afr[mi] = *(const s16x8*)(Ac + ar * 128 + (kb ^ ((ar & 7) << 4)));
            }
#pragma unroll
            for (int ni = 0; ni < 4; ++ni) {
                const int br = wn * 64 + ni * 16 + lr;
                bfr[ni] = *(const s16x8*)(Bc + br * 128 + (kb ^ ((br & 7) << 4)));
            }
#pragma unroll
            for (int mi = 0; mi < 4; ++mi)
#pragma unroll
                for (int ni = 0; ni < 4; ++ni) mfma_acc(acc[mi][ni], afr[mi], bfr[ni]);
        }
        if (kc < 7) {
#pragma unroll
            for (int it = 0; it < 4; ++it) {
                const int row = arow_t + it * 32;
                uint4 pk;
                pk.x = (unsigned int)f2bf(va[it].x) | ((unsigned int)f2bf(va[it].y) << 16);
                pk.y = (unsigned int)f2bf(va[it].z) | ((unsigned int)f2bf(va[it].w) << 16);
                pk.z = (unsigned int)f2bf(vb[it].x) | ((unsigned int)f2bf(vb[it].y) << 16);
                pk.w = (unsigned int)f2bf(vb[it].z) | ((unsigned int)f2bf(vb[it].w) << 16);
                *(uint4*)(An + row * 128 + ((au_t * 16) ^ ((row & 7) << 4))) = pk;
            }
        }
    }

    float aow[4];
#pragma unroll
    for (int ni = 0; ni < 4; ++ni) aow[ni] = ao[b * 512 + n0 + wn * 64 + ni * 16 + lr];
#pragma unroll
    for (int mi = 0; mi < 4; ++mi) {
#pragma unroll
        for (int r = 0; r < 4; ++r) {
            float p = 0.f;
#pragma unroll
            for (int ni = 0; ni < 4; ++ni) p += fast_tanh(acc[mi][ni][r]) * aow[ni];
            p += __shfl_xor(p, 1, 16);
            p += __shfl_xor(p, 2, 16);
            p += __shfl_xor(p, 4, 16);
            p += __shfl_xor(p, 8, 16);
            if (lr == 0)
                atomicAdd(&logit[(size_t)m0 + wm * 64 + mi * 16 + lq * 4 + r], p);
        }
    }
}

__global__ __launch_bounds__(256) void k_scatter(const float* logit, const int* stok,
                                                 const void* maskp, const int* flagp,
                                                 float* out, float* rowsum) {
    const int idx = blockIdx.x * 256 + threadIdx.x;
    const int b = idx >> 9;
    const int flag = *flagp;
    float v = 0.f;
    if (!get_mask(maskp, flag, idx)) {
        v = __expf(logit[idx]);
        atomicAdd(&out[(size_t)b * VX_ + stok[idx]], v);
    }
    float s = v;
#pragma unroll
    for (int o = 1; o < 64; o <<= 1) s += __shfl_xor(s, o, 64);
    if ((threadIdx.x & 63) == 0) atomicAdd(&rowsum[b], s);
}

__global__ __launch_bounds__(256) void k_final(float* out, const float* rowsum) {
    const int b = blockIdx.y;
    const float ls = logf(rowsum[b]);
    int v = blockIdx.x * 1024 + threadIdx.x;
#pragma unroll
    for (int i = 0; i < 4; ++i, v += 256) {
        if (v < VX_) {
            const size_t o = (size_t)b * VX_ + v;
            out[o] = logf(out[o]) - ls;
        }
    }
}

// ---- host ------------------------------------------------------------------

extern "C" void kernel_launch(void* const* d_in, const int* in_sizes, int n_in, void* d_out,
                              int out_size, void* d_ws, size_t ws_size, hipStream_t stream) {
    const float* embedding = (const float*)d_in[0];
    const float* W_ih = (const float*)d_in[1];
    const float* W_hh = (const float*)d_in[2];
    const float* b_ih = (const float*)d_in[3];
    const float* b_hh = (const float*)d_in[4];
    const float* W_attn = (const float*)d_in[5];
    const float* W_out = (const float*)d_in[6];
    const float* b_out = (const float*)d_in[7];
    const float* W_copy = (const float*)d_in[8];
    // d_in[9] = W_incopy: provably dead in the reference (tanh(0)=0 on unmatched,
    // matched positions masked to -inf => softmax is uniform over unmatched).
    const float* W_gen = (const float*)d_in[10];
    const float* enc = (const float*)d_in[11];
    const float* pcs = (const float*)d_in[12];
    const float* h0 = (const float*)d_in[13];
    const float* c0 = (const float*)d_in[14];
    const int* ptok = (const int*)d_in[15];
    const int* stok = (const int*)d_in[16];
    const void* maskp = d_in[17];
    float* out = (float*)d_out;

    char* ws = (char*)d_ws;
    size_t off = 0;
    auto alloc = [&](size_t bytes) {
        size_t o = off;
        off += (bytes + 255) & ~(size_t)255;
        return o;
    };
    int* flag = (int*)(ws + alloc(4));
    float* rowsum = (float*)(ws + alloc(B_ * 4));
    float* cs_sum = (float*)(ws + alloc((size_t)1024 * SRC_ * 4));
    int* cs_cnt = (int*)(ws + alloc(1024 * 4));
    unsigned short* xh = (unsigned short*)(ws + alloc((size_t)B_ * KXH * 2));
    unsigned short* Wg = (unsigned short*)(ws + alloc((size_t)2048 * KXH * 2));
    unsigned short* Wcb = (unsigned short*)(ws + alloc((size_t)512 * 512 * 2));
    float* gates = (float*)(ws + alloc((size_t)B_ * 2048 * 4));
    unsigned short* h1b = (unsigned short*)(ws + alloc((size_t)B_ * 512 * 2));
    float* qbuf = (float*)(ws + alloc((size_t)B_ * 512 * 4));
    float* parts = (float*)(ws + alloc((size_t)16 * B_ * 512 * 4));
    float* md = (float*)(ws + alloc((size_t)16 * B_ * 2 * 4));
    unsigned short* ch = (unsigned short*)(ws + alloc((size_t)B_ * 1024 * 2));
    unsigned short* aob = (unsigned short*)(ws + alloc((size_t)B_ * 512 * 2));
    float* logit = (float*)(ws + alloc((size_t)B_ * S_ * 4));
    const size_t ebf_bytes = (size_t)B_ * S_ * SRC_ * 2;  // 134 MB
    const int use_ebf = (off + ebf_bytes <= ws_size) ? 1 : 0;
    unsigned short* ebf = (unsigned short*)(ws + off);
    (void)n_in; (void)in_sizes; (void)out_size;

    hipLaunchKernelGGL(k_pre, dim3(2662), dim3(256), 0, stream, enc, stok, ptok, cs_sum, cs_cnt,
                       ebf, use_ebf, logit, rowsum, maskp, flag, out, W_ih, W_hh, W_copy, Wg,
                       Wcb, gates);
    hipLaunchKernelGGL(k_cs_final, dim3(256), dim3(256), 0, stream, cs_sum, cs_cnt, embedding,
                       ptok, pcs, h0, xh);
    hipLaunchKernelGGL(k_gates, dim3(4, 32, 2), dim3(256), 0, stream, xh, Wg, gates);
    hipLaunchKernelGGL(k_lstm, dim3(512), dim3(256), 0, stream, gates, b_ih, b_hh, c0, out, h1b);
    hipLaunchKernelGGL(k_q, dim3(4, 8), dim3(256), 0, stream, h1b, W_attn, qbuf);
    hipLaunchKernelGGL(k_attn2, dim3(4, 256), dim3(256), 0, stream, enc, ebf, use_ebf, qbuf,
                       maskp, flag, parts, md);
    hipLaunchKernelGGL(k_merge16, dim3(256), dim3(256), 0, stream, parts, md, h1b, ch);
    hipLaunchKernelGGL(k_attnout, dim3(4, 8), dim3(256), 0, stream, ch, W_out, b_out, out, aob);
    hipLaunchKernelGGL(k_gen, dim3(4, 782), dim3(256), 0, stream, aob, W_gen, out, rowsum);
    if (use_ebf) {
        hipLaunchKernelGGL(k_copyseq_bf, dim3(4, 1024), dim3(256), 0, stream, ebf, Wcb,
                           out + ATT_OFF, maskp, flag, logit);
    } else {
        hipLaunchKernelGGL(k_copyseq, dim3(1024, 4), dim3(256), 0, stream, enc, Wcb,
                           out + ATT_OFF, maskp, flag, logit);
    }
    hipLaunchKernelGGL(k_scatter, dim3(512), dim3(256), 0, stream, logit, stok, maskp, flag,
                       out, rowsum);
    hipLaunchKernelGGL(k_final, dim3(49, 256), dim3(256), 0, stream, out, rowsum);
}